// Round 9
// baseline (858.411 us; speedup 1.0000x reference)
//
#include <hip/hip_runtime.h>
#include <hip/hip_bf16.h>
#include <cstdint>
#include <cstddef>

#define NU 30000
#define NI 20000
#define NMASK 2000
#define NBUCK 2048

static inline int cdiv(int a, int b){ return (a + b - 1) / b; }

typedef __attribute__((ext_vector_type(8))) short bf16x8;
typedef __attribute__((ext_vector_type(4))) float f32x4;

// ===================== threefry-2x32 (exact JAX semantics) =====================
__device__ __forceinline__ uint32_t rotl32(uint32_t x, int r){ return (x<<r)|(x>>(32-r)); }

__device__ __forceinline__ void tf2x32(uint32_t k0, uint32_t k1,
                                       uint32_t x0, uint32_t x1,
                                       uint32_t& o0, uint32_t& o1)
{
  uint32_t k2 = k0 ^ k1 ^ 0x1BD11BDAu;
  x0 += k0; x1 += k1;
#define TFR(r) { x0 += x1; x1 = rotl32(x1,(r)); x1 ^= x0; }
  TFR(13) TFR(15) TFR(26) TFR(6)
  x0 += k1; x1 += k2 + 1u;
  TFR(17) TFR(29) TFR(16) TFR(24)
  x0 += k2; x1 += k0 + 2u;
  TFR(13) TFR(15) TFR(26) TFR(6)
  x0 += k0; x1 += k1 + 3u;
  TFR(17) TFR(29) TFR(16) TFR(24)
  x0 += k1; x1 += k2 + 4u;
  TFR(13) TFR(15) TFR(26) TFR(6)
  x0 += k2; x1 += k0 + 5u;
#undef TFR
  o0 = x0; o1 = x1;
}

// bits for BOTH shuffle rounds + bucket histograms, subkeys computed inline.
// partitionable: split(key)->subkey=tf(key,0,1), carry=tf(key,0,0); bits[i]=xor(tf(sub,0,i))
__global__ __launch_bounds__(256) void bits12_kernel(
    uint32_t* __restrict__ bits1, uint32_t* __restrict__ bits2,
    int* __restrict__ h1, int* __restrict__ h2, int n)
{
  int i = blockIdx.x*256 + threadIdx.x;
  if (i >= n) return;
  uint32_t c0,c1, s0,s1, t0,t1;
  tf2x32(0u,42u, 0u,0u, c0,c1);
  tf2x32(0u,42u, 0u,1u, s0,s1);
  tf2x32(c0,c1, 0u,1u, t0,t1);
  uint32_t o0,o1;
  tf2x32(s0,s1, 0u,(uint32_t)i, o0,o1);
  uint32_t b1 = o0^o1;
  tf2x32(t0,t1, 0u,(uint32_t)i, o0,o1);
  uint32_t b2 = o0^o1;
  bits1[i] = b1; bits2[i] = b2;
  atomicAdd(&h1[b1 >> 21], 1);
  atomicAdd(&h2[b2 >> 21], 1);
}

// two independent single-wave exclusive scans (block 0: h1->bb1, block 1: h2->bb2)
__global__ __launch_bounds__(64) void exscan2_kernel(
    const int* __restrict__ h1, int* __restrict__ bb1,
    const int* __restrict__ h2, int* __restrict__ bb2)
{
  const int* cnt = blockIdx.x ? h2 : h1;
  int* ptr = blockIdx.x ? bb2 : bb1;
  int lane = threadIdx.x;
  int carry = 0;
  for (int base = 0; base < NBUCK; base += 64) {
    int i = base + lane;
    int v = cnt[i];
    int s = v;
#pragma unroll
    for (int off = 1; off < 64; off <<= 1) {
      int t = __shfl_up(s, off);
      if (lane >= off) s += t;
    }
    ptr[i] = carry + s - v;
    carry += __shfl(s, 63);
  }
  if (lane == 0) ptr[NBUCK] = carry;
}

__global__ __launch_bounds__(256) void scatter12_kernel(
    const uint32_t* __restrict__ bits1, const int* __restrict__ bb1, int* __restrict__ c1,
    uint64_t* __restrict__ barr1,
    const uint32_t* __restrict__ bits2, const int* __restrict__ bb2, int* __restrict__ c2,
    uint64_t* __restrict__ barr2, int n)
{
  int i = blockIdx.x*256 + threadIdx.x;
  if (i >= n) return;
  uint32_t k1 = bits1[i];
  int b = k1 >> 21;
  int p = bb1[b] + atomicAdd(&c1[b], 1);
  barr1[p] = ((uint64_t)k1 << 32) | (uint32_t)i;
  uint32_t k2 = bits2[i];
  b = k2 >> 21;
  p = bb2[b] + atomicAdd(&c2[b], 1);
  barr2[p] = ((uint64_t)k2 << 32) | (uint32_t)i;
}

// rank = bucket_base + #{same-bucket pairs < mine}; u64 (key,idx) unique -> exact stable
template<int FINAL>
__global__ __launch_bounds__(256) void rank_bucket_kernel(
    const uint64_t* __restrict__ barr, const int* __restrict__ bptr,
    uint32_t* __restrict__ perm, float* __restrict__ mask_out, int* __restrict__ flag,
    int n)
{
  int p = blockIdx.x*256 + threadIdx.x;
  if (p >= n) return;
  uint64_t mk = barr[p];
  int b = (int)(mk >> 53);
  int p0 = bptr[b], p1 = bptr[b+1];
  int r = p0;
  for (int q = p0; q < p1; ++q) r += (int)(barr[q] < mk);
  uint32_t i = (uint32_t)mk;
  if (!FINAL) {
    perm[r] = i;
  } else if (r < NMASK) {
    uint32_t v = perm[i];
    mask_out[r] = (float)v;
    flag[v] = 1;
  }
}

// ===================== bf16 helpers (HW cvt, RNE) =====================
__device__ __forceinline__ ushort f2bf(float f){
  __hip_bfloat16 h = __float2bfloat16(f);
  return *reinterpret_cast<ushort*>(&h);
}
__device__ __forceinline__ uint32_t pk2(float a, float b){
  __hip_bfloat162 h = __float22bfloat162_rn(make_float2(a, b));
  return *reinterpret_cast<uint32_t*>(&h);
}
__device__ __forceinline__ uint2 f4_to_bf4(float4 v){
  __hip_bfloat162 h0 = __float22bfloat162_rn(make_float2(v.x, v.y));
  __hip_bfloat162 h1 = __float22bfloat162_rn(make_float2(v.z, v.w));
  return make_uint2(*reinterpret_cast<uint32_t*>(&h0), *reinterpret_cast<uint32_t*>(&h1));
}
__device__ __forceinline__ float lobf(uint32_t p){
  union { uint32_t u; float f; } c; c.u = p << 16; return c.f;
}
__device__ __forceinline__ float hibf(uint32_t p){
  union { uint32_t u; float f; } c; c.u = p & 0xffff0000u; return c.f;
}
__device__ __forceinline__ float bf2f(ushort h){
  union { uint32_t u; float f; } c; c.u = (uint32_t)h << 16; return c.f;
}

// convert all 4 weight matrices to bf16 once (segments: img | txt | itm | usr)
__global__ __launch_bounds__(256) void wcvt_kernel(
    const float* __restrict__ wi, const float* __restrict__ wt,
    const float* __restrict__ wm, const float* __restrict__ wu,
    ushort* __restrict__ wbf)
{
  const int n0 = 64*4096, n1 = 64*768, n2 = 64*1536, n3 = 64*1536;
  int i = blockIdx.x*256 + threadIdx.x;
  int total = n0+n1+n2+n3;
  for (; i < total; i += gridDim.x*256) {
    float v;
    if (i < n0) v = wi[i];
    else if (i < n0+n1) v = wt[i-n0];
    else if (i < n0+n1+n2) v = wm[i-n0-n1];
    else v = wu[i-n0-n1-n2];
    wbf[i] = f2bf(v);
  }
}

// ===================== MFMA GEMM: out(N,64) = X(N,K) @ W(64,K)^T =====================
// X staged to LDS (f32->bf16); W read directly from pre-converted bf16 global (L2-hot).
__global__ __launch_bounds__(256) void gemm_mfma_kernel(
    const float* __restrict__ X, const ushort* __restrict__ Wbf,
    float* __restrict__ pbuf, int N, int K, int klen)
{
  __shared__ ushort Xs[64][72];
  const int tid = threadIdx.x;
  const int row0 = blockIdx.x * 64;
  const int kbeg = blockIdx.y * klen;
  const int lane = tid & 63;
  const int wr = tid >> 6;
  const int lrow = lane & 15;
  const int kslot = lane >> 4;
  f32x4 acc[4] = {f32x4{0,0,0,0},f32x4{0,0,0,0},f32x4{0,0,0,0},f32x4{0,0,0,0}};

  const int sr = tid >> 4;
  const int sc = (tid & 15) * 4;

  for (int k0 = kbeg; k0 < kbeg + klen; k0 += 64) {
#pragma unroll
    for (int i = 0; i < 4; ++i) {
      int r = sr + 16*i;
      int gr = row0 + r;
      float4 v = make_float4(0.f,0.f,0.f,0.f);
      if (gr < N) v = *reinterpret_cast<const float4*>(X + (size_t)gr*K + k0 + sc);
      *reinterpret_cast<uint2*>(&Xs[r][sc]) = f4_to_bf4(v);
    }
    __syncthreads();
#pragma unroll
    for (int ks = 0; ks < 2; ++ks) {
      int kb = ks*32 + kslot*8;
      bf16x8 af = *reinterpret_cast<const bf16x8*>(&Xs[wr*16 + lrow][kb]);
#pragma unroll
      for (int ct = 0; ct < 4; ++ct) {
        bf16x8 bfr = *reinterpret_cast<const bf16x8*>(
            Wbf + (size_t)(ct*16 + lrow)*K + k0 + kb);
        acc[ct] = __builtin_amdgcn_mfma_f32_16x16x32_bf16(af, bfr, acc[ct], 0, 0, 0);
      }
    }
    __syncthreads();
  }
  float* pb = pbuf + (size_t)blockIdx.y * N * 64;
#pragma unroll
  for (int ct = 0; ct < 4; ++ct)
#pragma unroll
    for (int j = 0; j < 4; ++j) {
      int gr = row0 + wr*16 + kslot*4 + j;
      if (gr < N) pb[(size_t)gr*64 + ct*16 + lrow] = acc[ct][j];
    }
}

// out[r][c] = bias[c] + sum_ch pbuf[ch][r][c]; optional bf16 copy
__global__ __launch_bounds__(256) void gemm_reduce_kernel(
    const float* __restrict__ pbuf, const float* __restrict__ bias,
    float* __restrict__ out, ushort* __restrict__ obf, int N, int nch)
{
  int i = blockIdx.x*256 + threadIdx.x;
  if (i >= N*64) return;
  float s = bias[i & 63];
  for (int ch = 0; ch < nch; ++ch) s += pbuf[(size_t)ch*N*64 + i];
  out[i] = s;
  if (obf) obf[i] = f2bf(s);
}

// pack 4 item-side sources into interleaved uint2 + fused column means (3)
__global__ __launch_bounds__(256) void pack4_kernel(
    const float* __restrict__ a, const float* __restrict__ b,
    const float* __restrict__ c, const float* __restrict__ d,
    uint2* __restrict__ po, float* __restrict__ means, int n, float inv_n)
{
  __shared__ float red[3][256];
  int lane = threadIdx.x & 63;
  int w = threadIdx.x >> 6;
  float sa = 0.f, sb = 0.f, sc2 = 0.f;
  for (int r = blockIdx.x*4 + w; r < n; r += gridDim.x*4) {
    size_t i = (size_t)r*64 + lane;
    float av = a[i], bv = b[i], cv = c[i], dv = d[i];
    po[i] = make_uint2(pk2(av, bv), pk2(cv, dv));
    sa += av; sb += bv; sc2 += cv;
  }
  red[0][threadIdx.x] = sa; red[1][threadIdx.x] = sb; red[2][threadIdx.x] = sc2;
  __syncthreads();
  if (threadIdx.x < 64) {
#pragma unroll
    for (int q = 0; q < 3; ++q) {
      float t = red[q][lane]+red[q][64+lane]+red[q][128+lane]+red[q][192+lane];
      atomicAdd(&means[q*64+lane], t * inv_n);
    }
  }
}

// ===================== CSR build =====================
__global__ __launch_bounds__(256) void hist_kernel(const int* __restrict__ rows,
                                                   const int* __restrict__ cols,
                                                   int* __restrict__ cu, int* __restrict__ ci, int nnz)
{
  int k = blockIdx.x*256 + threadIdx.x;
  if (k < nnz) { atomicAdd(&cu[rows[k]], 1); atomicAdd(&ci[cols[k]], 1); }
}

__global__ __launch_bounds__(256) void scan_block_kernel(
    const int* __restrict__ cnt, int* __restrict__ part, int* __restrict__ bsum, int n)
{
  __shared__ int wsum[4];
  int i = blockIdx.x*256 + threadIdx.x;
  int lane = threadIdx.x & 63;
  int w = threadIdx.x >> 6;
  int v = (i < n) ? cnt[i] : 0;
  int s = v;
#pragma unroll
  for (int off = 1; off < 64; off <<= 1) {
    int t = __shfl_up(s, off);
    if (lane >= off) s += t;
  }
  if (lane == 63) wsum[w] = s;
  __syncthreads();
  int wo = 0;
#pragma unroll
  for (int k = 0; k < 4; ++k) if (k < w) wo += wsum[k];
  if (i < n) part[i] = wo + s - v;
  if (threadIdx.x == 255) bsum[blockIdx.x] = wo + s;
}

__global__ __launch_bounds__(64) void exscan_kernel(const int* __restrict__ cnt,
                                                    int* __restrict__ ptr, int n)
{
  int lane = threadIdx.x;
  int carry = 0;
  for (int base = 0; base < n; base += 64) {
    int i = base + lane;
    int v = (i < n) ? cnt[i] : 0;
    int s = v;
#pragma unroll
    for (int off = 1; off < 64; off <<= 1) {
      int t = __shfl_up(s, off);
      if (lane >= off) s += t;
    }
    if (i < n) ptr[i] = carry + s - v;
    carry += __shfl(s, 63);
  }
  if (lane == 0) ptr[n] = carry;
}

__global__ __launch_bounds__(256) void scan_add_kernel(
    const int* __restrict__ part, const int* __restrict__ bptr,
    int* __restrict__ ptr, int n, int nb)
{
  int i = blockIdx.x*256 + threadIdx.x;
  if (i < n) ptr[i] = part[i] + bptr[blockIdx.x];
  if (i == 0) ptr[n] = bptr[nb];
}

__global__ __launch_bounds__(256) void scatter_kernel(
    const int* __restrict__ rows, const int* __restrict__ cols, const float* __restrict__ vals,
    int* __restrict__ cur_u, int* __restrict__ cur_i,
    int* __restrict__ idx_u, float* __restrict__ val_u,
    int* __restrict__ idx_i, float* __restrict__ val_i, int nnz)
{
  int k = blockIdx.x*256 + threadIdx.x;
  if (k < nnz) {
    int r = rows[k], c = cols[k];
    float v = vals[k];
    int pu = atomicAdd(&cur_u[r], 1);
    idx_u[pu] = c; val_u[pu] = v;
    int pi = atomicAdd(&cur_i[c], 1);
    idx_i[pi] = r; val_i[pi] = v;
  }
}

// ===================== fused SpMMs (uint2 bf16 gathers) =====================
__global__ __launch_bounds__(256) void spmm_user1_kernel(
    const int* __restrict__ ptr, const int* __restrict__ idx, const float* __restrict__ val,
    const uint2* __restrict__ pka,
    const int* __restrict__ flag, const float* __restrict__ means,
    float* __restrict__ iu, float* __restrict__ tu, float* __restrict__ ufi, float* __restrict__ u1,
    uint2* __restrict__ qa, int nrows)
{
  int row = blockIdx.x*4 + (threadIdx.x >> 6);
  int lane = threadIdx.x & 63;
  if (row >= nrows) return;
  int p0 = ptr[row], p1 = ptr[row+1];
  float m0 = means[lane], m1 = means[64+lane], m2 = means[128+lane];
  float a0=0.f, a1=0.f, a2=0.f, a3=0.f;
  for (int p = p0; p < p1; ++p) {
    int j = idx[p]; float v = val[p];
    uint2 g = pka[(size_t)j*64 + lane];
    float x0, x1, x2, x3 = hibf(g.y);
    if (flag[j]) { x0 = m0; x1 = m1; x2 = m2; }
    else { x0 = lobf(g.x); x1 = hibf(g.x); x2 = lobf(g.y); }
    a0 = fmaf(v, x0, a0); a1 = fmaf(v, x1, a1);
    a2 = fmaf(v, x2, a2); a3 = fmaf(v, x3, a3);
  }
  size_t o = (size_t)row*64 + lane;
  iu[o]=a0; tu[o]=a1; ufi[o]=a2; u1[o]=a3;
  qa[o] = make_uint2(pk2(a0, a1), pk2(a2, a3));
}

__global__ __launch_bounds__(256) void spmm_item1_kernel(
    const int* __restrict__ ptr, const int* __restrict__ idx, const float* __restrict__ val,
    const uint2* __restrict__ qa, const ushort* __restrict__ ueh,
    float* __restrict__ ii, float* __restrict__ ti, float* __restrict__ ifo,
    float* __restrict__ i1, float* __restrict__ ip,
    uint32_t* __restrict__ qip1, int nrows)
{
  int row = blockIdx.x*4 + (threadIdx.x >> 6);
  int lane = threadIdx.x & 63;
  if (row >= nrows) return;
  int p0 = ptr[row], p1 = ptr[row+1];
  float a0=0.f, a1=0.f, a2=0.f, a3=0.f, a4=0.f;
  for (int p = p0; p < p1; ++p) {
    int j = idx[p]; float v = val[p];
    size_t b = (size_t)j*64 + lane;
    uint2 g = qa[b];
    float x4 = bf2f(ueh[b]);
    a0 = fmaf(v, lobf(g.x), a0); a1 = fmaf(v, hibf(g.x), a1);
    a2 = fmaf(v, lobf(g.y), a2); a3 = fmaf(v, hibf(g.y), a3);
    a4 = fmaf(v, x4, a4);
  }
  size_t o = (size_t)row*64 + lane;
  ii[o]=a0; ti[o]=a1; ifo[o]=a2; i1[o]=a3; ip[o]=a4;
  qip1[o] = pk2(a4, a3);
}

__global__ __launch_bounds__(256) void user2_kernel(
    const int* __restrict__ ptr, const int* __restrict__ idx, const float* __restrict__ val,
    const uint32_t* __restrict__ qip1,
    const float* __restrict__ idemb, const float* __restrict__ u1,
    const float* __restrict__ iu, const float* __restrict__ tu, const float* __restrict__ ufi,
    float* __restrict__ up, ushort* __restrict__ u2h, float* __restrict__ ug, int nrows)
{
  int row = blockIdx.x*4 + (threadIdx.x >> 6);
  int lane = threadIdx.x & 63;
  if (row >= nrows) return;
  int p0 = ptr[row], p1 = ptr[row+1];
  float aup=0.f, au2=0.f;
  for (int p = p0; p < p1; ++p) {
    int j = idx[p]; float v = val[p];
    uint32_t g = qip1[(size_t)j*64 + lane];
    aup = fmaf(v, lobf(g), aup);
    au2 = fmaf(v, hibf(g), au2);
  }
  float m = au2;
#pragma unroll
  for (int o2=32;o2;o2>>=1) m = fmaxf(m, __shfl_xor(m, o2));
  float e = expf(au2 - m);
  float s = e;
#pragma unroll
  for (int o2=32;o2;o2>>=1) s += __shfl_xor(s, o2);
  float u2 = e / s;
  size_t o = (size_t)row*64 + lane;
  up[o] = aup; u2h[o] = f2bf(u2);
  float e0 = idemb[o], e1 = u1[o];
  float v1 = iu[o], v2 = tu[o], v3 = aup, v4 = ufi[o];
  float n1=v1*v1, n2=v2*v2, n3=v3*v3, n4=v4*v4;
#pragma unroll
  for (int o2=32;o2;o2>>=1) {
    n1 += __shfl_xor(n1, o2); n2 += __shfl_xor(n2, o2);
    n3 += __shfl_xor(n3, o2); n4 += __shfl_xor(n4, o2);
  }
  n1 = fmaxf(sqrtf(n1), 1e-12f); n2 = fmaxf(sqrtf(n2), 1e-12f);
  n3 = fmaxf(sqrtf(n3), 1e-12f); n4 = fmaxf(sqrtf(n4), 1e-12f);
  ug[o] = (e0+e1+u2)*(1.f/3.f)
        + 0.02f*(v1/n1) + 0.02f*(v2/n2)
        + 0.30f*(v3/n3) + 0.30f*(v4/n4);
}

__global__ __launch_bounds__(256) void item2_kernel(
    const int* __restrict__ ptr, const int* __restrict__ idx, const float* __restrict__ val,
    const ushort* __restrict__ u2h,
    const float* __restrict__ idemb, const float* __restrict__ i1,
    const float* __restrict__ ii, const float* __restrict__ ti,
    const float* __restrict__ ip, const float* __restrict__ ifo,
    float* __restrict__ ig, int nrows)
{
  int row = blockIdx.x*4 + (threadIdx.x >> 6);
  int lane = threadIdx.x & 63;
  if (row >= nrows) return;
  int p0 = ptr[row], p1 = ptr[row+1];
  float ai2=0.f;
  for (int p = p0; p < p1; ++p) {
    int j = idx[p]; float v = val[p];
    ai2 = fmaf(v, bf2f(u2h[(size_t)j*64 + lane]), ai2);
  }
  float m = ai2;
#pragma unroll
  for (int o2=32;o2;o2>>=1) m = fmaxf(m, __shfl_xor(m, o2));
  float e = expf(ai2 - m);
  float s = e;
#pragma unroll
  for (int o2=32;o2;o2>>=1) s += __shfl_xor(s, o2);
  float i2 = e / s;
  size_t o = (size_t)row*64 + lane;
  float e0 = idemb[o], e1 = i1[o];
  float v1 = ii[o], v2 = ti[o], v3 = ip[o], v4 = ifo[o];
  float n1=v1*v1, n2=v2*v2, n3=v3*v3, n4=v4*v4;
#pragma unroll
  for (int o2=32;o2;o2>>=1) {
    n1 += __shfl_xor(n1, o2); n2 += __shfl_xor(n2, o2);
    n3 += __shfl_xor(n3, o2); n4 += __shfl_xor(n4, o2);
  }
  n1 = fmaxf(sqrtf(n1), 1e-12f); n2 = fmaxf(sqrtf(n2), 1e-12f);
  n3 = fmaxf(sqrtf(n3), 1e-12f); n4 = fmaxf(sqrtf(n4), 1e-12f);
  ig[o] = (e0+e1+i2)*(1.f/3.f)
        + 0.02f*(v1/n1) + 0.02f*(v2/n2)
        + 0.30f*(v3/n3) + 0.30f*(v4/n4);
}

// ===================== host =====================
extern "C" void kernel_launch(void* const* d_in, const int* in_sizes, int n_in,
                              void* d_out, int out_size, void* d_ws, size_t ws_size,
                              hipStream_t stream)
{
  const int*   ui_rows     = (const int*)d_in[0];
  const int*   ui_cols     = (const int*)d_in[1];
  const float* ui_vals     = (const float*)d_in[2];
  const float* image_feats = (const float*)d_in[3];
  const float* text_feats  = (const float*)d_in[4];
  const float* user_feats0 = (const float*)d_in[5];
  const float* item_title  = (const float*)d_in[6];
  const float* W_img = (const float*)d_in[7];
  const float* b_img = (const float*)d_in[8];
  const float* W_txt = (const float*)d_in[9];
  const float* b_txt = (const float*)d_in[10];
  const float* W_usr = (const float*)d_in[11];
  const float* b_usr = (const float*)d_in[12];
  const float* W_itm = (const float*)d_in[13];
  const float* b_itm = (const float*)d_in[14];
  const float* user_id_emb = (const float*)d_in[15];
  const float* item_id_emb = (const float*)d_in[16];
  const int nnz = in_sizes[0];

  float* out = (float*)d_out;
  const size_t OU = (size_t)NU*64, OI = (size_t)NI*64;
  size_t off = 0;
  float* o_ug   = out + off; off += OU;
  float* o_ig   = out + off; off += OI;
  float* o_ii   = out + off; off += OI;
  float* o_ti   = out + off; off += OI;
  float* o_iu   = out + off; off += OU;
  float* o_tu   = out + off; off += OU;
  float* o_ue   = out + off; off += OU;
  float* o_ifo  = out + off; off += OI;
  float* o_up   = out + off; off += OU;
  float* o_ip   = out + off; off += OI;
  float* o_ufi  = out + off; off += OU;
  float* o_mask = out + off; off += NMASK;
  float* o_ri   = out + off; off += OI;
  float* o_rt   = out + off; off += OI;
  float* o_rit  = out + off; off += OI;

  char* wp = (char*)d_ws;
  auto walloc = [&](size_t bytes) -> char* {
    char* r = wp; wp += (bytes + 255) & ~(size_t)255; return r;
  };
  // --- zero zone ---
  int*   cnt_u = (int*)  walloc((size_t)NU*4);
  int*   cnt_i = (int*)  walloc((size_t)NI*4);
  int*   flag  = (int*)  walloc((size_t)NI*4);
  float* means = (float*)walloc(3*64*4);
  int*   h1    = (int*)  walloc(NBUCK*4);
  int*   c1    = (int*)  walloc(NBUCK*4);
  int*   h2    = (int*)  walloc(NBUCK*4);
  int*   c2    = (int*)  walloc(NBUCK*4);
  size_t zero_bytes = (size_t)(wp - (char*)d_ws);
  // --- rest ---
  uint32_t* bits1 = (uint32_t*)walloc((size_t)NI*4);
  uint32_t* bits2 = (uint32_t*)walloc((size_t)NI*4);
  uint32_t* permA = (uint32_t*)walloc((size_t)NI*4);
  uint64_t* barr1 = (uint64_t*)walloc((size_t)NI*8);
  uint64_t* barr2 = (uint64_t*)walloc((size_t)NI*8);
  int*   bb1   = (int*)  walloc((NBUCK+1)*4);
  int*   bb2   = (int*)  walloc((NBUCK+1)*4);
  int*   ptr_u = (int*)  walloc((size_t)(NU+1)*4);
  int*   ptr_i = (int*)  walloc((size_t)(NI+1)*4);
  int*   cur_u = (int*)  walloc((size_t)NU*4);
  int*   cur_i = (int*)  walloc((size_t)NI*4);
  int*   idx_u = (int*)  walloc((size_t)nnz*4);
  float* val_u = (float*)walloc((size_t)nnz*4);
  int*   idx_i = (int*)  walloc((size_t)nnz*4);
  float* val_i = (float*)walloc((size_t)nnz*4);
  float* u1    = (float*)walloc(OU*4);
  float* i1    = (float*)walloc(OI*4);
  int*   part  = (int*)  walloc((size_t)NU*4);
  int*   bsum  = (int*)  walloc(256*4);
  int*   bptr  = (int*)  walloc(257*4);
  ushort* wbf  = (ushort*)walloc((size_t)64*(4096+768+1536+1536)*2);
  uint2* pk_all = (uint2*)walloc(OI*8);
  uint2* q_all  = (uint2*)walloc(OU*8);
  uint32_t* qip1 = (uint32_t*)walloc(OI*4);
  ushort*   ue_bf = (ushort*)walloc(OU*2);
  ushort*   u2h   = (ushort*)walloc(OU*2);
  float* pbuf  = (float*)walloc((size_t)8*NU*64*4);
  ushort* wbf_img = wbf;
  ushort* wbf_txt = wbf + 64*4096;
  ushort* wbf_itm = wbf_txt + 64*768;
  ushort* wbf_usr = wbf_itm + 64*1536;

  hipMemsetAsync(d_ws, 0, zero_bytes, stream);

  // --- mask_nodes: exact JAX permutation(key(42), 20000)[:2000], bucketed stable sorts ---
  const int GB = cdiv(NI,256);
  bits12_kernel<<<GB, 256, 0, stream>>>(bits1, bits2, h1, h2, NI);
  exscan2_kernel<<<2, 64, 0, stream>>>(h1, bb1, h2, bb2);
  scatter12_kernel<<<GB, 256, 0, stream>>>(bits1, bb1, c1, barr1, bits2, bb2, c2, barr2, NI);
  rank_bucket_kernel<0><<<GB, 256, 0, stream>>>(barr1, bb1, permA, nullptr, nullptr, NI);
  rank_bucket_kernel<1><<<GB, 256, 0, stream>>>(barr2, bb2, permA, o_mask, flag, NI);

  // --- weights to bf16 once ---
  wcvt_kernel<<<512, 256, 0, stream>>>(W_img, W_txt, W_itm, W_usr, wbf);

  // --- raw projections (bf16 MFMA, K-split, W direct-from-global) ---
  auto gemm = [&](const float* X, const ushort* Wb, const float* b, float* o, ushort* obf,
                  int N, int K, int nch){
    dim3 g(cdiv(N,64), nch);
    gemm_mfma_kernel<<<g, 256, 0, stream>>>(X, Wb, pbuf, N, K, K/nch);
    gemm_reduce_kernel<<<cdiv(N*64,256), 256, 0, stream>>>(pbuf, b, o, obf, N, nch);
  };
  gemm(image_feats, wbf_img, b_img, o_ri,  nullptr, NI, 4096, 8);
  gemm(text_feats,  wbf_txt, b_txt, o_rt,  nullptr, NI, 768,  4);
  gemm(item_title,  wbf_itm, b_itm, o_rit, nullptr, NI, 1536, 4);
  gemm(user_feats0, wbf_usr, b_usr, o_ue,  ue_bf,   NU, 1536, 6);

  // pack item-side gather table + fused column means
  pack4_kernel<<<128, 256, 0, stream>>>(o_ri, o_rt, o_rit, item_id_emb, pk_all, means, NI, 1.f/NI);

  // --- CSR build ---
  hist_kernel<<<cdiv(nnz,256), 256, 0, stream>>>(ui_rows, ui_cols, cnt_u, cnt_i, nnz);
  {
    int nbu = cdiv(NU,256);
    scan_block_kernel<<<nbu, 256, 0, stream>>>(cnt_u, part, bsum, NU);
    exscan_kernel<<<1, 64, 0, stream>>>(bsum, bptr, nbu);
    scan_add_kernel<<<nbu, 256, 0, stream>>>(part, bptr, ptr_u, NU, nbu);
    int nbi = cdiv(NI,256);
    scan_block_kernel<<<nbi, 256, 0, stream>>>(cnt_i, part, bsum, NI);
    exscan_kernel<<<1, 64, 0, stream>>>(bsum, bptr, nbi);
    scan_add_kernel<<<nbi, 256, 0, stream>>>(part, bptr, ptr_i, NI, nbi);
  }
  hipMemcpyAsync(cur_u, ptr_u, (size_t)NU*4, hipMemcpyDeviceToDevice, stream);
  hipMemcpyAsync(cur_i, ptr_i, (size_t)NI*4, hipMemcpyDeviceToDevice, stream);
  scatter_kernel<<<cdiv(nnz,256), 256, 0, stream>>>(ui_rows, ui_cols, ui_vals,
      cur_u, cur_i, idx_u, val_u, idx_i, val_i, nnz);

  const int GU = cdiv(NU,4), GI = cdiv(NI,4);
  spmm_user1_kernel<<<GU,256,0,stream>>>(ptr_u, idx_u, val_u,
      pk_all, flag, means,
      o_iu, o_tu, o_ufi, u1, q_all, NU);
  spmm_item1_kernel<<<GI,256,0,stream>>>(ptr_i, idx_i, val_i,
      q_all, ue_bf,
      o_ii, o_ti, o_ifo, i1, o_ip, qip1, NI);
  user2_kernel<<<GU,256,0,stream>>>(ptr_u, idx_u, val_u,
      qip1, user_id_emb, u1, o_iu, o_tu, o_ufi,
      o_up, u2h, o_ug, NU);
  item2_kernel<<<GI,256,0,stream>>>(ptr_i, idx_i, val_i,
      u2h, item_id_emb, i1, o_ii, o_ti, o_ip, o_ifo,
      o_ig, NI);
}

// Round 10
// 724.166 us; speedup vs baseline: 1.1854x; 1.1854x over previous
//
#include <hip/hip_runtime.h>
#include <hip/hip_bf16.h>
#include <cstdint>
#include <cstddef>

#define NU 30000
#define NI 20000
#define NMASK 2000
#define NBUCK 2048

static inline int cdiv(int a, int b){ return (a + b - 1) / b; }

typedef __attribute__((ext_vector_type(8))) short bf16x8;
typedef __attribute__((ext_vector_type(4))) float f32x4;

// ===================== threefry-2x32 (exact JAX semantics) =====================
__device__ __forceinline__ uint32_t rotl32(uint32_t x, int r){ return (x<<r)|(x>>(32-r)); }

__device__ __forceinline__ void tf2x32(uint32_t k0, uint32_t k1,
                                       uint32_t x0, uint32_t x1,
                                       uint32_t& o0, uint32_t& o1)
{
  uint32_t k2 = k0 ^ k1 ^ 0x1BD11BDAu;
  x0 += k0; x1 += k1;
#define TFR(r) { x0 += x1; x1 = rotl32(x1,(r)); x1 ^= x0; }
  TFR(13) TFR(15) TFR(26) TFR(6)
  x0 += k1; x1 += k2 + 1u;
  TFR(17) TFR(29) TFR(16) TFR(24)
  x0 += k2; x1 += k0 + 2u;
  TFR(13) TFR(15) TFR(26) TFR(6)
  x0 += k0; x1 += k1 + 3u;
  TFR(17) TFR(29) TFR(16) TFR(24)
  x0 += k1; x1 += k2 + 4u;
  TFR(13) TFR(15) TFR(26) TFR(6)
  x0 += k2; x1 += k0 + 5u;
#undef TFR
  o0 = x0; o1 = x1;
}

// bits for BOTH shuffle rounds + bucket histograms, subkeys computed inline.
__global__ __launch_bounds__(256) void bits12_kernel(
    uint32_t* __restrict__ bits1, uint32_t* __restrict__ bits2,
    int* __restrict__ h1, int* __restrict__ h2, int n)
{
  int i = blockIdx.x*256 + threadIdx.x;
  if (i >= n) return;
  uint32_t c0,c1, s0,s1, t0,t1;
  tf2x32(0u,42u, 0u,0u, c0,c1);
  tf2x32(0u,42u, 0u,1u, s0,s1);
  tf2x32(c0,c1, 0u,1u, t0,t1);
  uint32_t o0,o1;
  tf2x32(s0,s1, 0u,(uint32_t)i, o0,o1);
  uint32_t b1 = o0^o1;
  tf2x32(t0,t1, 0u,(uint32_t)i, o0,o1);
  uint32_t b2 = o0^o1;
  bits1[i] = b1; bits2[i] = b2;
  atomicAdd(&h1[b1 >> 21], 1);
  atomicAdd(&h2[b2 >> 21], 1);
}

// two independent single-wave exclusive scans
__global__ __launch_bounds__(64) void exscan2_kernel(
    const int* __restrict__ h1, int* __restrict__ bb1,
    const int* __restrict__ h2, int* __restrict__ bb2)
{
  const int* cnt = blockIdx.x ? h2 : h1;
  int* ptr = blockIdx.x ? bb2 : bb1;
  int lane = threadIdx.x;
  int carry = 0;
  for (int base = 0; base < NBUCK; base += 64) {
    int i = base + lane;
    int v = cnt[i];
    int s = v;
#pragma unroll
    for (int off = 1; off < 64; off <<= 1) {
      int t = __shfl_up(s, off);
      if (lane >= off) s += t;
    }
    ptr[i] = carry + s - v;
    carry += __shfl(s, 63);
  }
  if (lane == 0) ptr[NBUCK] = carry;
}

__global__ __launch_bounds__(256) void scatter12_kernel(
    const uint32_t* __restrict__ bits1, const int* __restrict__ bb1, int* __restrict__ c1,
    uint64_t* __restrict__ barr1,
    const uint32_t* __restrict__ bits2, const int* __restrict__ bb2, int* __restrict__ c2,
    uint64_t* __restrict__ barr2, int n)
{
  int i = blockIdx.x*256 + threadIdx.x;
  if (i >= n) return;
  uint32_t k1 = bits1[i];
  int b = k1 >> 21;
  int p = bb1[b] + atomicAdd(&c1[b], 1);
  barr1[p] = ((uint64_t)k1 << 32) | (uint32_t)i;
  uint32_t k2 = bits2[i];
  b = k2 >> 21;
  p = bb2[b] + atomicAdd(&c2[b], 1);
  barr2[p] = ((uint64_t)k2 << 32) | (uint32_t)i;
}

// rank = bucket_base + #{same-bucket pairs < mine}; u64 (key,idx) unique -> exact stable
template<int FINAL>
__global__ __launch_bounds__(256) void rank_bucket_kernel(
    const uint64_t* __restrict__ barr, const int* __restrict__ bptr,
    uint32_t* __restrict__ perm, float* __restrict__ mask_out, int* __restrict__ flag,
    int n)
{
  int p = blockIdx.x*256 + threadIdx.x;
  if (p >= n) return;
  uint64_t mk = barr[p];
  int b = (int)(mk >> 53);
  int p0 = bptr[b], p1 = bptr[b+1];
  int r = p0;
  for (int q = p0; q < p1; ++q) r += (int)(barr[q] < mk);
  uint32_t i = (uint32_t)mk;
  if (!FINAL) {
    perm[r] = i;
  } else if (r < NMASK) {
    uint32_t v = perm[i];
    mask_out[r] = (float)v;
    flag[v] = 1;
  }
}

// ===================== bf16 helpers (HW cvt, RNE) =====================
__device__ __forceinline__ ushort f2bf(float f){
  __hip_bfloat16 h = __float2bfloat16(f);
  return *reinterpret_cast<ushort*>(&h);
}
__device__ __forceinline__ uint32_t pk2(float a, float b){
  __hip_bfloat162 h = __float22bfloat162_rn(make_float2(a, b));
  return *reinterpret_cast<uint32_t*>(&h);
}
__device__ __forceinline__ uint2 f4_to_bf4(float4 v){
  __hip_bfloat162 h0 = __float22bfloat162_rn(make_float2(v.x, v.y));
  __hip_bfloat162 h1 = __float22bfloat162_rn(make_float2(v.z, v.w));
  return make_uint2(*reinterpret_cast<uint32_t*>(&h0), *reinterpret_cast<uint32_t*>(&h1));
}
__device__ __forceinline__ float lobf(uint32_t p){
  union { uint32_t u; float f; } c; c.u = p << 16; return c.f;
}
__device__ __forceinline__ float hibf(uint32_t p){
  union { uint32_t u; float f; } c; c.u = p & 0xffff0000u; return c.f;
}
__device__ __forceinline__ float bf2f(ushort h){
  union { uint32_t u; float f; } c; c.u = (uint32_t)h << 16; return c.f;
}

// convert all 4 weight matrices to bf16 once (segments: img | txt | itm | usr)
__global__ __launch_bounds__(256) void wcvt_kernel(
    const float* __restrict__ wi, const float* __restrict__ wt,
    const float* __restrict__ wm, const float* __restrict__ wu,
    ushort* __restrict__ wbf)
{
  const int n0 = 64*4096, n1 = 64*768, n2 = 64*1536, n3 = 64*1536;
  int i = blockIdx.x*256 + threadIdx.x;
  int total = n0+n1+n2+n3;
  for (; i < total; i += gridDim.x*256) {
    float v;
    if (i < n0) v = wi[i];
    else if (i < n0+n1) v = wt[i-n0];
    else if (i < n0+n1+n2) v = wm[i-n0-n1];
    else v = wu[i-n0-n1-n2];
    wbf[i] = f2bf(v);
  }
}

// ===================== MFMA GEMM: out(N,64) = X(N,K) @ W(64,K)^T =====================
// X staged to LDS (f32->bf16 cvt); W staged to LDS from pre-converted bf16 global (pure copy).
__global__ __launch_bounds__(256) void gemm_mfma_kernel(
    const float* __restrict__ X, const ushort* __restrict__ Wbf,
    float* __restrict__ pbuf, int N, int K, int klen)
{
  __shared__ ushort Xs[64][72];
  __shared__ ushort Ws[64][72];
  const int tid = threadIdx.x;
  const int row0 = blockIdx.x * 64;
  const int kbeg = blockIdx.y * klen;
  const int lane = tid & 63;
  const int wr = tid >> 6;
  const int lrow = lane & 15;
  const int kslot = lane >> 4;
  f32x4 acc[4] = {f32x4{0,0,0,0},f32x4{0,0,0,0},f32x4{0,0,0,0},f32x4{0,0,0,0}};

  const int sr = tid >> 4;          // X staging row 0..15 (+16i)
  const int sc = (tid & 15) * 4;    // X staging col (floats)
  const int wrow = tid >> 2;        // W staging row 0..63
  const int wcol = (tid & 3) * 16;  // W staging col (elements), 2 x uint4

  for (int k0 = kbeg; k0 < kbeg + klen; k0 += 64) {
#pragma unroll
    for (int i = 0; i < 4; ++i) {
      int r = sr + 16*i;
      int gr = row0 + r;
      float4 v = make_float4(0.f,0.f,0.f,0.f);
      if (gr < N) v = *reinterpret_cast<const float4*>(X + (size_t)gr*K + k0 + sc);
      *reinterpret_cast<uint2*>(&Xs[r][sc]) = f4_to_bf4(v);
    }
    {
      const ushort* wsrc = Wbf + (size_t)wrow*K + k0 + wcol;
      *reinterpret_cast<uint4*>(&Ws[wrow][wcol])   = *reinterpret_cast<const uint4*>(wsrc);
      *reinterpret_cast<uint4*>(&Ws[wrow][wcol+8]) = *reinterpret_cast<const uint4*>(wsrc + 8);
    }
    __syncthreads();
#pragma unroll
    for (int ks = 0; ks < 2; ++ks) {
      int kb = ks*32 + kslot*8;
      bf16x8 af = *reinterpret_cast<const bf16x8*>(&Xs[wr*16 + lrow][kb]);
#pragma unroll
      for (int ct = 0; ct < 4; ++ct) {
        bf16x8 bfr = *reinterpret_cast<const bf16x8*>(&Ws[ct*16 + lrow][kb]);
        acc[ct] = __builtin_amdgcn_mfma_f32_16x16x32_bf16(af, bfr, acc[ct], 0, 0, 0);
      }
    }
    __syncthreads();
  }
  float* pb = pbuf + (size_t)blockIdx.y * N * 64;
#pragma unroll
  for (int ct = 0; ct < 4; ++ct)
#pragma unroll
    for (int j = 0; j < 4; ++j) {
      int gr = row0 + wr*16 + kslot*4 + j;
      if (gr < N) pb[(size_t)gr*64 + ct*16 + lrow] = acc[ct][j];
    }
}

// out[r][c] = bias[c] + sum_ch pbuf[ch][r][c]; optional bf16 copy
__global__ __launch_bounds__(256) void gemm_reduce_kernel(
    const float* __restrict__ pbuf, const float* __restrict__ bias,
    float* __restrict__ out, ushort* __restrict__ obf, int N, int nch)
{
  int i = blockIdx.x*256 + threadIdx.x;
  if (i >= N*64) return;
  float s = bias[i & 63];
  for (int ch = 0; ch < nch; ++ch) s += pbuf[(size_t)ch*N*64 + i];
  out[i] = s;
  if (obf) obf[i] = f2bf(s);
}

// pack 4 item-side sources into interleaved uint2 + fused column means (3)
__global__ __launch_bounds__(256) void pack4_kernel(
    const float* __restrict__ a, const float* __restrict__ b,
    const float* __restrict__ c, const float* __restrict__ d,
    uint2* __restrict__ po, float* __restrict__ means, int n, float inv_n)
{
  __shared__ float red[3][256];
  int lane = threadIdx.x & 63;
  int w = threadIdx.x >> 6;
  float sa = 0.f, sb = 0.f, sc2 = 0.f;
  for (int r = blockIdx.x*4 + w; r < n; r += gridDim.x*4) {
    size_t i = (size_t)r*64 + lane;
    float av = a[i], bv = b[i], cv = c[i], dv = d[i];
    po[i] = make_uint2(pk2(av, bv), pk2(cv, dv));
    sa += av; sb += bv; sc2 += cv;
  }
  red[0][threadIdx.x] = sa; red[1][threadIdx.x] = sb; red[2][threadIdx.x] = sc2;
  __syncthreads();
  if (threadIdx.x < 64) {
#pragma unroll
    for (int q = 0; q < 3; ++q) {
      float t = red[q][lane]+red[q][64+lane]+red[q][128+lane]+red[q][192+lane];
      atomicAdd(&means[q*64+lane], t * inv_n);
    }
  }
}

// ===================== CSR build =====================
__global__ __launch_bounds__(256) void hist_kernel(const int* __restrict__ rows,
                                                   const int* __restrict__ cols,
                                                   int* __restrict__ cu, int* __restrict__ ci, int nnz)
{
  int k = blockIdx.x*256 + threadIdx.x;
  if (k < nnz) { atomicAdd(&cu[rows[k]], 1); atomicAdd(&ci[cols[k]], 1); }
}

__global__ __launch_bounds__(256) void scan_block_kernel(
    const int* __restrict__ cnt, int* __restrict__ part, int* __restrict__ bsum, int n)
{
  __shared__ int wsum[4];
  int i = blockIdx.x*256 + threadIdx.x;
  int lane = threadIdx.x & 63;
  int w = threadIdx.x >> 6;
  int v = (i < n) ? cnt[i] : 0;
  int s = v;
#pragma unroll
  for (int off = 1; off < 64; off <<= 1) {
    int t = __shfl_up(s, off);
    if (lane >= off) s += t;
  }
  if (lane == 63) wsum[w] = s;
  __syncthreads();
  int wo = 0;
#pragma unroll
  for (int k = 0; k < 4; ++k) if (k < w) wo += wsum[k];
  if (i < n) part[i] = wo + s - v;
  if (threadIdx.x == 255) bsum[blockIdx.x] = wo + s;
}

__global__ __launch_bounds__(64) void exscan_kernel(const int* __restrict__ cnt,
                                                    int* __restrict__ ptr, int n)
{
  int lane = threadIdx.x;
  int carry = 0;
  for (int base = 0; base < n; base += 64) {
    int i = base + lane;
    int v = (i < n) ? cnt[i] : 0;
    int s = v;
#pragma unroll
    for (int off = 1; off < 64; off <<= 1) {
      int t = __shfl_up(s, off);
      if (lane >= off) s += t;
    }
    if (i < n) ptr[i] = carry + s - v;
    carry += __shfl(s, 63);
  }
  if (lane == 0) ptr[n] = carry;
}

__global__ __launch_bounds__(256) void scan_add_kernel(
    const int* __restrict__ part, const int* __restrict__ bptr,
    int* __restrict__ ptr, int n, int nb)
{
  int i = blockIdx.x*256 + threadIdx.x;
  if (i < n) ptr[i] = part[i] + bptr[blockIdx.x];
  if (i == 0) ptr[n] = bptr[nb];
}

__global__ __launch_bounds__(256) void scatter_kernel(
    const int* __restrict__ rows, const int* __restrict__ cols, const float* __restrict__ vals,
    int* __restrict__ cur_u, int* __restrict__ cur_i,
    int* __restrict__ idx_u, float* __restrict__ val_u,
    int* __restrict__ idx_i, float* __restrict__ val_i, int nnz)
{
  int k = blockIdx.x*256 + threadIdx.x;
  if (k < nnz) {
    int r = rows[k], c = cols[k];
    float v = vals[k];
    int pu = atomicAdd(&cur_u[r], 1);
    idx_u[pu] = c; val_u[pu] = v;
    int pi = atomicAdd(&cur_i[c], 1);
    idx_i[pi] = r; val_i[pi] = v;
  }
}

// ===================== fused SpMMs (uint2 bf16 gathers) =====================
__global__ __launch_bounds__(256) void spmm_user1_kernel(
    const int* __restrict__ ptr, const int* __restrict__ idx, const float* __restrict__ val,
    const uint2* __restrict__ pka,
    const int* __restrict__ flag, const float* __restrict__ means,
    float* __restrict__ iu, float* __restrict__ tu, float* __restrict__ ufi, float* __restrict__ u1,
    uint2* __restrict__ qa, int nrows)
{
  int row = blockIdx.x*4 + (threadIdx.x >> 6);
  int lane = threadIdx.x & 63;
  if (row >= nrows) return;
  int p0 = ptr[row], p1 = ptr[row+1];
  float m0 = means[lane], m1 = means[64+lane], m2 = means[128+lane];
  float a0=0.f, a1=0.f, a2=0.f, a3=0.f;
  for (int p = p0; p < p1; ++p) {
    int j = idx[p]; float v = val[p];
    uint2 g = pka[(size_t)j*64 + lane];
    float x0, x1, x2, x3 = hibf(g.y);
    if (flag[j]) { x0 = m0; x1 = m1; x2 = m2; }
    else { x0 = lobf(g.x); x1 = hibf(g.x); x2 = lobf(g.y); }
    a0 = fmaf(v, x0, a0); a1 = fmaf(v, x1, a1);
    a2 = fmaf(v, x2, a2); a3 = fmaf(v, x3, a3);
  }
  size_t o = (size_t)row*64 + lane;
  iu[o]=a0; tu[o]=a1; ufi[o]=a2; u1[o]=a3;
  qa[o] = make_uint2(pk2(a0, a1), pk2(a2, a3));
}

__global__ __launch_bounds__(256) void spmm_item1_kernel(
    const int* __restrict__ ptr, const int* __restrict__ idx, const float* __restrict__ val,
    const uint2* __restrict__ qa, const ushort* __restrict__ ueh,
    float* __restrict__ ii, float* __restrict__ ti, float* __restrict__ ifo,
    float* __restrict__ i1, float* __restrict__ ip,
    uint32_t* __restrict__ qip1, int nrows)
{
  int row = blockIdx.x*4 + (threadIdx.x >> 6);
  int lane = threadIdx.x & 63;
  if (row >= nrows) return;
  int p0 = ptr[row], p1 = ptr[row+1];
  float a0=0.f, a1=0.f, a2=0.f, a3=0.f, a4=0.f;
  for (int p = p0; p < p1; ++p) {
    int j = idx[p]; float v = val[p];
    size_t b = (size_t)j*64 + lane;
    uint2 g = qa[b];
    float x4 = bf2f(ueh[b]);
    a0 = fmaf(v, lobf(g.x), a0); a1 = fmaf(v, hibf(g.x), a1);
    a2 = fmaf(v, lobf(g.y), a2); a3 = fmaf(v, hibf(g.y), a3);
    a4 = fmaf(v, x4, a4);
  }
  size_t o = (size_t)row*64 + lane;
  ii[o]=a0; ti[o]=a1; ifo[o]=a2; i1[o]=a3; ip[o]=a4;
  qip1[o] = pk2(a4, a3);
}

__global__ __launch_bounds__(256) void user2_kernel(
    const int* __restrict__ ptr, const int* __restrict__ idx, const float* __restrict__ val,
    const uint32_t* __restrict__ qip1,
    const float* __restrict__ idemb, const float* __restrict__ u1,
    const float* __restrict__ iu, const float* __restrict__ tu, const float* __restrict__ ufi,
    float* __restrict__ up, ushort* __restrict__ u2h, float* __restrict__ ug, int nrows)
{
  int row = blockIdx.x*4 + (threadIdx.x >> 6);
  int lane = threadIdx.x & 63;
  if (row >= nrows) return;
  int p0 = ptr[row], p1 = ptr[row+1];
  float aup=0.f, au2=0.f;
  for (int p = p0; p < p1; ++p) {
    int j = idx[p]; float v = val[p];
    uint32_t g = qip1[(size_t)j*64 + lane];
    aup = fmaf(v, lobf(g), aup);
    au2 = fmaf(v, hibf(g), au2);
  }
  float m = au2;
#pragma unroll
  for (int o2=32;o2;o2>>=1) m = fmaxf(m, __shfl_xor(m, o2));
  float e = expf(au2 - m);
  float s = e;
#pragma unroll
  for (int o2=32;o2;o2>>=1) s += __shfl_xor(s, o2);
  float u2 = e / s;
  size_t o = (size_t)row*64 + lane;
  up[o] = aup; u2h[o] = f2bf(u2);
  float e0 = idemb[o], e1 = u1[o];
  float v1 = iu[o], v2 = tu[o], v3 = aup, v4 = ufi[o];
  float n1=v1*v1, n2=v2*v2, n3=v3*v3, n4=v4*v4;
#pragma unroll
  for (int o2=32;o2;o2>>=1) {
    n1 += __shfl_xor(n1, o2); n2 += __shfl_xor(n2, o2);
    n3 += __shfl_xor(n3, o2); n4 += __shfl_xor(n4, o2);
  }
  n1 = fmaxf(sqrtf(n1), 1e-12f); n2 = fmaxf(sqrtf(n2), 1e-12f);
  n3 = fmaxf(sqrtf(n3), 1e-12f); n4 = fmaxf(sqrtf(n4), 1e-12f);
  ug[o] = (e0+e1+u2)*(1.f/3.f)
        + 0.02f*(v1/n1) + 0.02f*(v2/n2)
        + 0.30f*(v3/n3) + 0.30f*(v4/n4);
}

__global__ __launch_bounds__(256) void item2_kernel(
    const int* __restrict__ ptr, const int* __restrict__ idx, const float* __restrict__ val,
    const ushort* __restrict__ u2h,
    const float* __restrict__ idemb, const float* __restrict__ i1,
    const float* __restrict__ ii, const float* __restrict__ ti,
    const float* __restrict__ ip, const float* __restrict__ ifo,
    float* __restrict__ ig, int nrows)
{
  int row = blockIdx.x*4 + (threadIdx.x >> 6);
  int lane = threadIdx.x & 63;
  if (row >= nrows) return;
  int p0 = ptr[row], p1 = ptr[row+1];
  float ai2=0.f;
  for (int p = p0; p < p1; ++p) {
    int j = idx[p]; float v = val[p];
    ai2 = fmaf(v, bf2f(u2h[(size_t)j*64 + lane]), ai2);
  }
  float m = ai2;
#pragma unroll
  for (int o2=32;o2;o2>>=1) m = fmaxf(m, __shfl_xor(m, o2));
  float e = expf(ai2 - m);
  float s = e;
#pragma unroll
  for (int o2=32;o2;o2>>=1) s += __shfl_xor(s, o2);
  float i2 = e / s;
  size_t o = (size_t)row*64 + lane;
  float e0 = idemb[o], e1 = i1[o];
  float v1 = ii[o], v2 = ti[o], v3 = ip[o], v4 = ifo[o];
  float n1=v1*v1, n2=v2*v2, n3=v3*v3, n4=v4*v4;
#pragma unroll
  for (int o2=32;o2;o2>>=1) {
    n1 += __shfl_xor(n1, o2); n2 += __shfl_xor(n2, o2);
    n3 += __shfl_xor(n3, o2); n4 += __shfl_xor(n4, o2);
  }
  n1 = fmaxf(sqrtf(n1), 1e-12f); n2 = fmaxf(sqrtf(n2), 1e-12f);
  n3 = fmaxf(sqrtf(n3), 1e-12f); n4 = fmaxf(sqrtf(n4), 1e-12f);
  ig[o] = (e0+e1+i2)*(1.f/3.f)
        + 0.02f*(v1/n1) + 0.02f*(v2/n2)
        + 0.30f*(v3/n3) + 0.30f*(v4/n4);
}

// ===================== host =====================
extern "C" void kernel_launch(void* const* d_in, const int* in_sizes, int n_in,
                              void* d_out, int out_size, void* d_ws, size_t ws_size,
                              hipStream_t stream)
{
  const int*   ui_rows     = (const int*)d_in[0];
  const int*   ui_cols     = (const int*)d_in[1];
  const float* ui_vals     = (const float*)d_in[2];
  const float* image_feats = (const float*)d_in[3];
  const float* text_feats  = (const float*)d_in[4];
  const float* user_feats0 = (const float*)d_in[5];
  const float* item_title  = (const float*)d_in[6];
  const float* W_img = (const float*)d_in[7];
  const float* b_img = (const float*)d_in[8];
  const float* W_txt = (const float*)d_in[9];
  const float* b_txt = (const float*)d_in[10];
  const float* W_usr = (const float*)d_in[11];
  const float* b_usr = (const float*)d_in[12];
  const float* W_itm = (const float*)d_in[13];
  const float* b_itm = (const float*)d_in[14];
  const float* user_id_emb = (const float*)d_in[15];
  const float* item_id_emb = (const float*)d_in[16];
  const int nnz = in_sizes[0];

  float* out = (float*)d_out;
  const size_t OU = (size_t)NU*64, OI = (size_t)NI*64;
  size_t off = 0;
  float* o_ug   = out + off; off += OU;
  float* o_ig   = out + off; off += OI;
  float* o_ii   = out + off; off += OI;
  float* o_ti   = out + off; off += OI;
  float* o_iu   = out + off; off += OU;
  float* o_tu   = out + off; off += OU;
  float* o_ue   = out + off; off += OU;
  float* o_ifo  = out + off; off += OI;
  float* o_up   = out + off; off += OU;
  float* o_ip   = out + off; off += OI;
  float* o_ufi  = out + off; off += OU;
  float* o_mask = out + off; off += NMASK;
  float* o_ri   = out + off; off += OI;
  float* o_rt   = out + off; off += OI;
  float* o_rit  = out + off; off += OI;

  char* wp = (char*)d_ws;
  auto walloc = [&](size_t bytes) -> char* {
    char* r = wp; wp += (bytes + 255) & ~(size_t)255; return r;
  };
  // --- zero zone ---
  int*   cnt_u = (int*)  walloc((size_t)NU*4);
  int*   cnt_i = (int*)  walloc((size_t)NI*4);
  int*   flag  = (int*)  walloc((size_t)NI*4);
  float* means = (float*)walloc(3*64*4);
  int*   h1    = (int*)  walloc(NBUCK*4);
  int*   c1    = (int*)  walloc(NBUCK*4);
  int*   h2    = (int*)  walloc(NBUCK*4);
  int*   c2    = (int*)  walloc(NBUCK*4);
  size_t zero_bytes = (size_t)(wp - (char*)d_ws);
  // --- rest ---
  uint32_t* bits1 = (uint32_t*)walloc((size_t)NI*4);
  uint32_t* bits2 = (uint32_t*)walloc((size_t)NI*4);
  uint32_t* permA = (uint32_t*)walloc((size_t)NI*4);
  uint64_t* barr1 = (uint64_t*)walloc((size_t)NI*8);
  uint64_t* barr2 = (uint64_t*)walloc((size_t)NI*8);
  int*   bb1   = (int*)  walloc((NBUCK+1)*4);
  int*   bb2   = (int*)  walloc((NBUCK+1)*4);
  int*   ptr_u = (int*)  walloc((size_t)(NU+1)*4);
  int*   ptr_i = (int*)  walloc((size_t)(NI+1)*4);
  int*   cur_u = (int*)  walloc((size_t)NU*4);
  int*   cur_i = (int*)  walloc((size_t)NI*4);
  int*   idx_u = (int*)  walloc((size_t)nnz*4);
  float* val_u = (float*)walloc((size_t)nnz*4);
  int*   idx_i = (int*)  walloc((size_t)nnz*4);
  float* val_i = (float*)walloc((size_t)nnz*4);
  float* u1    = (float*)walloc(OU*4);
  float* i1    = (float*)walloc(OI*4);
  int*   part  = (int*)  walloc((size_t)NU*4);
  int*   bsum  = (int*)  walloc(256*4);
  int*   bptr  = (int*)  walloc(257*4);
  ushort* wbf  = (ushort*)walloc((size_t)64*(4096+768+1536+1536)*2);
  uint2* pk_all = (uint2*)walloc(OI*8);
  uint2* q_all  = (uint2*)walloc(OU*8);
  uint32_t* qip1 = (uint32_t*)walloc(OI*4);
  ushort*   ue_bf = (ushort*)walloc(OU*2);
  ushort*   u2h   = (ushort*)walloc(OU*2);
  float* pbuf  = (float*)walloc((size_t)8*NU*64*4);
  ushort* wbf_img = wbf;
  ushort* wbf_txt = wbf + 64*4096;
  ushort* wbf_itm = wbf_txt + 64*768;
  ushort* wbf_usr = wbf_itm + 64*1536;

  hipMemsetAsync(d_ws, 0, zero_bytes, stream);

  // --- mask_nodes: exact JAX permutation(key(42), 20000)[:2000], bucketed stable sorts ---
  const int GB = cdiv(NI,256);
  bits12_kernel<<<GB, 256, 0, stream>>>(bits1, bits2, h1, h2, NI);
  exscan2_kernel<<<2, 64, 0, stream>>>(h1, bb1, h2, bb2);
  scatter12_kernel<<<GB, 256, 0, stream>>>(bits1, bb1, c1, barr1, bits2, bb2, c2, barr2, NI);
  rank_bucket_kernel<0><<<GB, 256, 0, stream>>>(barr1, bb1, permA, nullptr, nullptr, NI);
  rank_bucket_kernel<1><<<GB, 256, 0, stream>>>(barr2, bb2, permA, o_mask, flag, NI);

  // --- weights to bf16 once ---
  wcvt_kernel<<<512, 256, 0, stream>>>(W_img, W_txt, W_itm, W_usr, wbf);

  // --- raw projections (bf16 MFMA, K-split, W staged from bf16 global) ---
  auto gemm = [&](const float* X, const ushort* Wb, const float* b, float* o, ushort* obf,
                  int N, int K, int nch){
    dim3 g(cdiv(N,64), nch);
    gemm_mfma_kernel<<<g, 256, 0, stream>>>(X, Wb, pbuf, N, K, K/nch);
    gemm_reduce_kernel<<<cdiv(N*64,256), 256, 0, stream>>>(pbuf, b, o, obf, N, nch);
  };
  gemm(image_feats, wbf_img, b_img, o_ri,  nullptr, NI, 4096, 8);
  gemm(text_feats,  wbf_txt, b_txt, o_rt,  nullptr, NI, 768,  4);
  gemm(item_title,  wbf_itm, b_itm, o_rit, nullptr, NI, 1536, 4);
  gemm(user_feats0, wbf_usr, b_usr, o_ue,  ue_bf,   NU, 1536, 6);

  // pack item-side gather table + fused column means
  pack4_kernel<<<128, 256, 0, stream>>>(o_ri, o_rt, o_rit, item_id_emb, pk_all, means, NI, 1.f/NI);

  // --- CSR build ---
  hist_kernel<<<cdiv(nnz,256), 256, 0, stream>>>(ui_rows, ui_cols, cnt_u, cnt_i, nnz);
  {
    int nbu = cdiv(NU,256);
    scan_block_kernel<<<nbu, 256, 0, stream>>>(cnt_u, part, bsum, NU);
    exscan_kernel<<<1, 64, 0, stream>>>(bsum, bptr, nbu);
    scan_add_kernel<<<nbu, 256, 0, stream>>>(part, bptr, ptr_u, NU, nbu);
    int nbi = cdiv(NI,256);
    scan_block_kernel<<<nbi, 256, 0, stream>>>(cnt_i, part, bsum, NI);
    exscan_kernel<<<1, 64, 0, stream>>>(bsum, bptr, nbi);
    scan_add_kernel<<<nbi, 256, 0, stream>>>(part, bptr, ptr_i, NI, nbi);
  }
  hipMemcpyAsync(cur_u, ptr_u, (size_t)NU*4, hipMemcpyDeviceToDevice, stream);
  hipMemcpyAsync(cur_i, ptr_i, (size_t)NI*4, hipMemcpyDeviceToDevice, stream);
  scatter_kernel<<<cdiv(nnz,256), 256, 0, stream>>>(ui_rows, ui_cols, ui_vals,
      cur_u, cur_i, idx_u, val_u, idx_i, val_i, nnz);

  const int GU = cdiv(NU,4), GI = cdiv(NI,4);
  spmm_user1_kernel<<<GU,256,0,stream>>>(ptr_u, idx_u, val_u,
      pk_all, flag, means,
      o_iu, o_tu, o_ufi, u1, q_all, NU);
  spmm_item1_kernel<<<GI,256,0,stream>>>(ptr_i, idx_i, val_i,
      q_all, ue_bf,
      o_ii, o_ti, o_ifo, i1, o_ip, qip1, NI);
  user2_kernel<<<GU,256,0,stream>>>(ptr_u, idx_u, val_u,
      qip1, user_id_emb, u1, o_iu, o_tu, o_ufi,
      o_up, u2h, o_ug, NU);
  item2_kernel<<<GI,256,0,stream>>>(ptr_i, idx_i, val_i,
      u2h, item_id_emb, i1, o_ii, o_ti, o_ip, o_ifo,
      o_ig, NI);
}

// Round 11
// 578.122 us; speedup vs baseline: 1.4848x; 1.2526x over previous
//
#include <hip/hip_runtime.h>
#include <hip/hip_bf16.h>
#include <cstdint>
#include <cstddef>

#define NU 30000
#define NI 20000
#define NMASK 2000
#define NBUCK 2048

static inline int cdiv(int a, int b){ return (a + b - 1) / b; }

typedef __attribute__((ext_vector_type(8))) short bf16x8;
typedef __attribute__((ext_vector_type(4))) float f32x4;

// ===================== threefry-2x32 (exact JAX semantics) =====================
__device__ __forceinline__ uint32_t rotl32(uint32_t x, int r){ return (x<<r)|(x>>(32-r)); }

__device__ __forceinline__ void tf2x32(uint32_t k0, uint32_t k1,
                                       uint32_t x0, uint32_t x1,
                                       uint32_t& o0, uint32_t& o1)
{
  uint32_t k2 = k0 ^ k1 ^ 0x1BD11BDAu;
  x0 += k0; x1 += k1;
#define TFR(r) { x0 += x1; x1 = rotl32(x1,(r)); x1 ^= x0; }
  TFR(13) TFR(15) TFR(26) TFR(6)
  x0 += k1; x1 += k2 + 1u;
  TFR(17) TFR(29) TFR(16) TFR(24)
  x0 += k2; x1 += k0 + 2u;
  TFR(13) TFR(15) TFR(26) TFR(6)
  x0 += k0; x1 += k1 + 3u;
  TFR(17) TFR(29) TFR(16) TFR(24)
  x0 += k1; x1 += k2 + 4u;
  TFR(13) TFR(15) TFR(26) TFR(6)
  x0 += k2; x1 += k0 + 5u;
#undef TFR
  o0 = x0; o1 = x1;
}

// ===================== bf16 helpers (HW cvt, RNE) =====================
__device__ __forceinline__ ushort f2bf(float f){
  __hip_bfloat16 h = __float2bfloat16(f);
  return *reinterpret_cast<ushort*>(&h);
}
__device__ __forceinline__ uint32_t pk2(float a, float b){
  __hip_bfloat162 h = __float22bfloat162_rn(make_float2(a, b));
  return *reinterpret_cast<uint32_t*>(&h);
}
__device__ __forceinline__ uint2 f4_to_bf4(float4 v){
  __hip_bfloat162 h0 = __float22bfloat162_rn(make_float2(v.x, v.y));
  __hip_bfloat162 h1 = __float22bfloat162_rn(make_float2(v.z, v.w));
  return make_uint2(*reinterpret_cast<uint32_t*>(&h0), *reinterpret_cast<uint32_t*>(&h1));
}
__device__ __forceinline__ float lobf(uint32_t p){
  union { uint32_t u; float f; } c; c.u = p << 16; return c.f;
}
__device__ __forceinline__ float hibf(uint32_t p){
  union { uint32_t u; float f; } c; c.u = p & 0xffff0000u; return c.f;
}
__device__ __forceinline__ float bf2f(ushort h){
  union { uint32_t u; float f; } c; c.u = (uint32_t)h << 16; return c.f;
}

// ===================== prep: threefry bits (both rounds) + bucket hists + W->bf16 =====================
#define WTOTAL (64*(4096+768+1536+1536))
__global__ __launch_bounds__(256) void prep_kernel(
    uint32_t* __restrict__ bits1, uint32_t* __restrict__ bits2,
    int* __restrict__ h1, int* __restrict__ h2,
    const float* __restrict__ wi, const float* __restrict__ wt,
    const float* __restrict__ wm, const float* __restrict__ wu,
    ushort* __restrict__ wbf)
{
  int i = blockIdx.x*256 + threadIdx.x;
  if (i < NI) {
    uint32_t c0,c1, s0,s1, t0,t1;
    tf2x32(0u,42u, 0u,0u, c0,c1);
    tf2x32(0u,42u, 0u,1u, s0,s1);
    tf2x32(c0,c1, 0u,1u, t0,t1);
    uint32_t o0,o1;
    tf2x32(s0,s1, 0u,(uint32_t)i, o0,o1);
    uint32_t b1 = o0^o1;
    tf2x32(t0,t1, 0u,(uint32_t)i, o0,o1);
    uint32_t b2 = o0^o1;
    bits1[i] = b1; bits2[i] = b2;
    atomicAdd(&h1[b1 >> 21], 1);
    atomicAdd(&h2[b2 >> 21], 1);
  }
  const int n0 = 64*4096, n1 = 64*768, n2 = 64*1536;
  for (int k = i; k < WTOTAL; k += gridDim.x*256) {
    float v;
    if (k < n0) v = wi[k];
    else if (k < n0+n1) v = wt[k-n0];
    else if (k < n0+n1+n2) v = wm[k-n0-n1];
    else v = wu[k-n0-n1-n2];
    wbf[k] = f2bf(v);
  }
}

// two independent single-wave exclusive scans over the bucket hists
__global__ __launch_bounds__(64) void exscan2_kernel(
    const int* __restrict__ h1, int* __restrict__ bb1,
    const int* __restrict__ h2, int* __restrict__ bb2)
{
  const int* cnt = blockIdx.x ? h2 : h1;
  int* ptr = blockIdx.x ? bb2 : bb1;
  int lane = threadIdx.x;
  int carry = 0;
  for (int base = 0; base < NBUCK; base += 64) {
    int i = base + lane;
    int v = cnt[i];
    int s = v;
#pragma unroll
    for (int off = 1; off < 64; off <<= 1) {
      int t = __shfl_up(s, off);
      if (lane >= off) s += t;
    }
    ptr[i] = carry + s - v;
    carry += __shfl(s, 63);
  }
  if (lane == 0) ptr[NBUCK] = carry;
}

__global__ __launch_bounds__(256) void scatter12_kernel(
    const uint32_t* __restrict__ bits1, const int* __restrict__ bb1, int* __restrict__ c1,
    uint64_t* __restrict__ barr1,
    const uint32_t* __restrict__ bits2, const int* __restrict__ bb2, int* __restrict__ c2,
    uint64_t* __restrict__ barr2, int n)
{
  int i = blockIdx.x*256 + threadIdx.x;
  if (i >= n) return;
  uint32_t k1 = bits1[i];
  int b = k1 >> 21;
  int p = bb1[b] + atomicAdd(&c1[b], 1);
  barr1[p] = ((uint64_t)k1 << 32) | (uint32_t)i;
  uint32_t k2 = bits2[i];
  b = k2 >> 21;
  p = bb2[b] + atomicAdd(&c2[b], 1);
  barr2[p] = ((uint64_t)k2 << 32) | (uint32_t)i;
}

// rank = bucket_base + #{same-bucket pairs < mine}; u64 (key,idx) unique -> exact stable
template<int FINAL>
__global__ __launch_bounds__(256) void rank_bucket_kernel(
    const uint64_t* __restrict__ barr, const int* __restrict__ bptr,
    uint32_t* __restrict__ perm, float* __restrict__ mask_out, int* __restrict__ flag,
    int n)
{
  int p = blockIdx.x*256 + threadIdx.x;
  if (p >= n) return;
  uint64_t mk = barr[p];
  int b = (int)(mk >> 53);
  int p0 = bptr[b], p1 = bptr[b+1];
  int r = p0;
  for (int q = p0; q < p1; ++q) r += (int)(barr[q] < mk);
  uint32_t i = (uint32_t)mk;
  if (!FINAL) {
    perm[r] = i;
  } else if (r < NMASK) {
    uint32_t v = perm[i];
    mask_out[r] = (float)v;
    flag[v] = 1;
  }
}

// ===================== MFMA GEMM: out(N,64) = X(N,K) @ W(64,K)^T =====================
__global__ __launch_bounds__(256) void gemm_mfma_kernel(
    const float* __restrict__ X, const ushort* __restrict__ Wbf,
    float* __restrict__ pbuf, int N, int K, int klen)
{
  __shared__ ushort Xs[64][72];
  __shared__ ushort Ws[64][72];
  const int tid = threadIdx.x;
  const int row0 = blockIdx.x * 64;
  const int kbeg = blockIdx.y * klen;
  const int lane = tid & 63;
  const int wr = tid >> 6;
  const int lrow = lane & 15;
  const int kslot = lane >> 4;
  f32x4 acc[4] = {f32x4{0,0,0,0},f32x4{0,0,0,0},f32x4{0,0,0,0},f32x4{0,0,0,0}};

  const int sr = tid >> 4;
  const int sc = (tid & 15) * 4;
  const int wrow = tid >> 2;
  const int wcol = (tid & 3) * 16;

  for (int k0 = kbeg; k0 < kbeg + klen; k0 += 64) {
#pragma unroll
    for (int i = 0; i < 4; ++i) {
      int r = sr + 16*i;
      int gr = row0 + r;
      float4 v = make_float4(0.f,0.f,0.f,0.f);
      if (gr < N) v = *reinterpret_cast<const float4*>(X + (size_t)gr*K + k0 + sc);
      *reinterpret_cast<uint2*>(&Xs[r][sc]) = f4_to_bf4(v);
    }
    {
      const ushort* wsrc = Wbf + (size_t)wrow*K + k0 + wcol;
      *reinterpret_cast<uint4*>(&Ws[wrow][wcol])   = *reinterpret_cast<const uint4*>(wsrc);
      *reinterpret_cast<uint4*>(&Ws[wrow][wcol+8]) = *reinterpret_cast<const uint4*>(wsrc + 8);
    }
    __syncthreads();
#pragma unroll
    for (int ks = 0; ks < 2; ++ks) {
      int kb = ks*32 + kslot*8;
      bf16x8 af = *reinterpret_cast<const bf16x8*>(&Xs[wr*16 + lrow][kb]);
#pragma unroll
      for (int ct = 0; ct < 4; ++ct) {
        bf16x8 bfr = *reinterpret_cast<const bf16x8*>(&Ws[ct*16 + lrow][kb]);
        acc[ct] = __builtin_amdgcn_mfma_f32_16x16x32_bf16(af, bfr, acc[ct], 0, 0, 0);
      }
    }
    __syncthreads();
  }
  float* pb = pbuf + (size_t)blockIdx.y * N * 64;
#pragma unroll
  for (int ct = 0; ct < 4; ++ct)
#pragma unroll
    for (int j = 0; j < 4; ++j) {
      int gr = row0 + wr*16 + kslot*4 + j;
      if (gr < N) pb[(size_t)gr*64 + ct*16 + lrow] = acc[ct][j];
    }
}

// ===================== fused reduce for all 4 GEMMs + pack + column means =====================
__global__ __launch_bounds__(256) void reduce4_kernel(
    const float* __restrict__ pb_img, const float* __restrict__ pb_txt,
    const float* __restrict__ pb_itm, const float* __restrict__ pb_usr,
    const float* __restrict__ b_img, const float* __restrict__ b_txt,
    const float* __restrict__ b_itm, const float* __restrict__ b_usr,
    const float* __restrict__ idemb,
    float* __restrict__ o_ri, float* __restrict__ o_rt, float* __restrict__ o_rit,
    float* __restrict__ o_ue, ushort* __restrict__ ue_bf,
    uint2* __restrict__ pk_all, float* __restrict__ means)
{
  __shared__ float red[3][256];
  const int nI = NI*64, nUx = NU*64;
  int lane = threadIdx.x & 63;
  int w = threadIdx.x >> 6;
  float sa = 0.f, sb = 0.f, sc = 0.f;
  for (int i = blockIdx.x*256 + threadIdx.x; i < nUx; i += gridDim.x*256) {
    int lc = i & 63;
    if (i < nI) {
      float s = b_img[lc];
#pragma unroll
      for (int c = 0; c < 8; ++c) s += pb_img[(size_t)c*nI + i];
      o_ri[i] = s;
      float t = b_txt[lc];
#pragma unroll
      for (int c = 0; c < 4; ++c) t += pb_txt[(size_t)c*nI + i];
      o_rt[i] = t;
      float u = b_itm[lc];
#pragma unroll
      for (int c = 0; c < 4; ++c) u += pb_itm[(size_t)c*nI + i];
      o_rit[i] = u;
      pk_all[i] = make_uint2(pk2(s, t), pk2(u, idemb[i]));
      sa += s; sb += t; sc += u;
    }
    float su = b_usr[lc];
#pragma unroll
    for (int c = 0; c < 6; ++c) su += pb_usr[(size_t)c*nUx + i];
    o_ue[i] = su; ue_bf[i] = f2bf(su);
  }
  red[0][threadIdx.x] = sa; red[1][threadIdx.x] = sb; red[2][threadIdx.x] = sc;
  __syncthreads();
  if (threadIdx.x < 64) {
#pragma unroll
    for (int q = 0; q < 3; ++q) {
      float t = red[q][lane]+red[q][64+lane]+red[q][128+lane]+red[q][192+lane];
      if (t != 0.f) atomicAdd(&means[q*64+lane], t * (1.f/NI));
    }
  }
}

// ===================== CSR build =====================
__global__ __launch_bounds__(256) void hist_kernel(const int* __restrict__ rows,
                                                   const int* __restrict__ cols,
                                                   int* __restrict__ cu, int* __restrict__ ci, int nnz)
{
  int k = blockIdx.x*256 + threadIdx.x;
  if (k < nnz) { atomicAdd(&cu[rows[k]], 1); atomicAdd(&ci[cols[k]], 1); }
}

// dual per-block exclusive scan (user blocks first, then item blocks)
__global__ __launch_bounds__(256) void scan_block2_kernel(
    const int* __restrict__ cnt_u, const int* __restrict__ cnt_i,
    int* __restrict__ part_u, int* __restrict__ part_i,
    int* __restrict__ bsum_u, int* __restrict__ bsum_i, int nbu)
{
  __shared__ int wsum[4];
  bool isU = (int)blockIdx.x < nbu;
  int blk = isU ? blockIdx.x : blockIdx.x - nbu;
  const int* cnt = isU ? cnt_u : cnt_i;
  int* part = isU ? part_u : part_i;
  int* bsum = isU ? bsum_u : bsum_i;
  int n = isU ? NU : NI;
  int i = blk*256 + threadIdx.x;
  int lane = threadIdx.x & 63;
  int w = threadIdx.x >> 6;
  int v = (i < n) ? cnt[i] : 0;
  int s = v;
#pragma unroll
  for (int off = 1; off < 64; off <<= 1) {
    int t = __shfl_up(s, off);
    if (lane >= off) s += t;
  }
  if (lane == 63) wsum[w] = s;
  __syncthreads();
  int wo = 0;
#pragma unroll
  for (int k = 0; k < 4; ++k) if (k < w) wo += wsum[k];
  if (i < n) part[i] = wo + s - v;
  if (threadIdx.x == 255) bsum[blk] = wo + s;
}

// dual single-wave scans of block sums
__global__ __launch_bounds__(64) void exscan2b_kernel(
    const int* __restrict__ bs_u, int* __restrict__ bp_u, int nbu,
    const int* __restrict__ bs_i, int* __restrict__ bp_i, int nbi)
{
  const int* cnt = blockIdx.x ? bs_i : bs_u;
  int* ptr = blockIdx.x ? bp_i : bp_u;
  int n = blockIdx.x ? nbi : nbu;
  int lane = threadIdx.x;
  int carry = 0;
  for (int base = 0; base < n; base += 64) {
    int i = base + lane;
    int v = (i < n) ? cnt[i] : 0;
    int s = v;
#pragma unroll
    for (int off = 1; off < 64; off <<= 1) {
      int t = __shfl_up(s, off);
      if (lane >= off) s += t;
    }
    if (i < n) ptr[i] = carry + s - v;
    carry += __shfl(s, 63);
  }
  if (lane == 0) ptr[n] = carry;
}

// dual add block offsets; writes ptr AND cur (scatter cursor copy)
__global__ __launch_bounds__(256) void scan_add2_kernel(
    const int* __restrict__ part_u, const int* __restrict__ bp_u,
    const int* __restrict__ part_i, const int* __restrict__ bp_i,
    int* __restrict__ ptr_u, int* __restrict__ cur_u,
    int* __restrict__ ptr_i, int* __restrict__ cur_i, int nbu, int nbi)
{
  bool isU = (int)blockIdx.x < nbu;
  int blk = isU ? blockIdx.x : blockIdx.x - nbu;
  int n = isU ? NU : NI;
  const int* part = isU ? part_u : part_i;
  const int* bp = isU ? bp_u : bp_i;
  int* ptr = isU ? ptr_u : ptr_i;
  int* cur = isU ? cur_u : cur_i;
  int i = blk*256 + threadIdx.x;
  if (i < n) { int v = part[i] + bp[blk]; ptr[i] = v; cur[i] = v; }
  if (i == 0) ptr[n] = bp[isU ? nbu : nbi];
}

__global__ __launch_bounds__(256) void scatter_kernel(
    const int* __restrict__ rows, const int* __restrict__ cols, const float* __restrict__ vals,
    int* __restrict__ cur_u, int* __restrict__ cur_i,
    int* __restrict__ idx_u, float* __restrict__ val_u,
    int* __restrict__ idx_i, float* __restrict__ val_i, int nnz)
{
  int k = blockIdx.x*256 + threadIdx.x;
  if (k < nnz) {
    int r = rows[k], c = cols[k];
    float v = vals[k];
    int pu = atomicAdd(&cur_u[r], 1);
    idx_u[pu] = c; val_u[pu] = v;
    int pi = atomicAdd(&cur_i[c], 1);
    idx_i[pi] = r; val_i[pi] = v;
  }
}

// ===================== fused SpMMs (uint2 bf16 gathers, 4-edge unroll for MLP) =====================
__global__ __launch_bounds__(256) void spmm_user1_kernel(
    const int* __restrict__ ptr, const int* __restrict__ idx, const float* __restrict__ val,
    const uint2* __restrict__ pka,
    const int* __restrict__ flag, const float* __restrict__ means,
    float* __restrict__ iu, float* __restrict__ tu, float* __restrict__ ufi, float* __restrict__ u1,
    uint2* __restrict__ qa, int nrows)
{
  int row = blockIdx.x*4 + (threadIdx.x >> 6);
  int lane = threadIdx.x & 63;
  if (row >= nrows) return;
  int p0 = ptr[row], p1 = ptr[row+1];
  float m0 = means[lane], m1 = means[64+lane], m2 = means[128+lane];
  float a0=0.f, a1=0.f, a2=0.f, a3=0.f;
#define U1STEP(gg,ff,ww) { float x0,x1,x2, x3 = hibf(gg.y); \
    if (ff) { x0=m0; x1=m1; x2=m2; } \
    else { x0=lobf(gg.x); x1=hibf(gg.x); x2=lobf(gg.y); } \
    a0=fmaf(ww,x0,a0); a1=fmaf(ww,x1,a1); a2=fmaf(ww,x2,a2); a3=fmaf(ww,x3,a3); }
  int p = p0;
  for (; p + 4 <= p1; p += 4) {
    int j0=idx[p+0], j1=idx[p+1], j2=idx[p+2], j3=idx[p+3];
    float w0=val[p+0], w1=val[p+1], w2=val[p+2], w3=val[p+3];
    int f0=flag[j0], f1=flag[j1], f2=flag[j2], f3=flag[j3];
    uint2 g0=pka[(size_t)j0*64+lane], g1=pka[(size_t)j1*64+lane];
    uint2 g2=pka[(size_t)j2*64+lane], g3=pka[(size_t)j3*64+lane];
    U1STEP(g0,f0,w0) U1STEP(g1,f1,w1) U1STEP(g2,f2,w2) U1STEP(g3,f3,w3)
  }
  for (; p < p1; ++p) {
    int j = idx[p]; float v = val[p];
    uint2 g = pka[(size_t)j*64 + lane];
    int f = flag[j];
    U1STEP(g,f,v)
  }
#undef U1STEP
  size_t o = (size_t)row*64 + lane;
  iu[o]=a0; tu[o]=a1; ufi[o]=a2; u1[o]=a3;
  qa[o] = make_uint2(pk2(a0, a1), pk2(a2, a3));
}

__global__ __launch_bounds__(256) void spmm_item1_kernel(
    const int* __restrict__ ptr, const int* __restrict__ idx, const float* __restrict__ val,
    const uint2* __restrict__ qa, const ushort* __restrict__ ueh,
    float* __restrict__ ii, float* __restrict__ ti, float* __restrict__ ifo,
    float* __restrict__ i1, float* __restrict__ ip,
    uint32_t* __restrict__ qip1, int nrows)
{
  int row = blockIdx.x*4 + (threadIdx.x >> 6);
  int lane = threadIdx.x & 63;
  if (row >= nrows) return;
  int p0 = ptr[row], p1 = ptr[row+1];
  float a0=0.f, a1=0.f, a2=0.f, a3=0.f, a4=0.f;
#define I1STEP(gg,uu,ww) { \
    a0=fmaf(ww,lobf(gg.x),a0); a1=fmaf(ww,hibf(gg.x),a1); \
    a2=fmaf(ww,lobf(gg.y),a2); a3=fmaf(ww,hibf(gg.y),a3); \
    a4=fmaf(ww,bf2f(uu),a4); }
  int p = p0;
  for (; p + 4 <= p1; p += 4) {
    int j0=idx[p+0], j1=idx[p+1], j2=idx[p+2], j3=idx[p+3];
    float w0=val[p+0], w1=val[p+1], w2=val[p+2], w3=val[p+3];
    size_t b0=(size_t)j0*64+lane, b1=(size_t)j1*64+lane, b2=(size_t)j2*64+lane, b3=(size_t)j3*64+lane;
    uint2 g0=qa[b0], g1=qa[b1], g2=qa[b2], g3=qa[b3];
    ushort u0=ueh[b0], u1_=ueh[b1], u2_=ueh[b2], u3_=ueh[b3];
    I1STEP(g0,u0,w0) I1STEP(g1,u1_,w1) I1STEP(g2,u2_,w2) I1STEP(g3,u3_,w3)
  }
  for (; p < p1; ++p) {
    int j = idx[p]; float v = val[p];
    size_t b = (size_t)j*64 + lane;
    uint2 g = qa[b]; ushort u = ueh[b];
    I1STEP(g,u,v)
  }
#undef I1STEP
  size_t o = (size_t)row*64 + lane;
  ii[o]=a0; ti[o]=a1; ifo[o]=a2; i1[o]=a3; ip[o]=a4;
  qip1[o] = pk2(a4, a3);
}

__global__ __launch_bounds__(256) void user2_kernel(
    const int* __restrict__ ptr, const int* __restrict__ idx, const float* __restrict__ val,
    const uint32_t* __restrict__ qip1,
    const float* __restrict__ idemb, const float* __restrict__ u1,
    const float* __restrict__ iu, const float* __restrict__ tu, const float* __restrict__ ufi,
    float* __restrict__ up, ushort* __restrict__ u2h, float* __restrict__ ug, int nrows)
{
  int row = blockIdx.x*4 + (threadIdx.x >> 6);
  int lane = threadIdx.x & 63;
  if (row >= nrows) return;
  int p0 = ptr[row], p1 = ptr[row+1];
  float aup=0.f, au2=0.f;
  int p = p0;
  for (; p + 4 <= p1; p += 4) {
    int j0=idx[p+0], j1=idx[p+1], j2=idx[p+2], j3=idx[p+3];
    float w0=val[p+0], w1=val[p+1], w2=val[p+2], w3=val[p+3];
    uint32_t g0=qip1[(size_t)j0*64+lane], g1=qip1[(size_t)j1*64+lane];
    uint32_t g2=qip1[(size_t)j2*64+lane], g3=qip1[(size_t)j3*64+lane];
    aup=fmaf(w0,lobf(g0),aup); au2=fmaf(w0,hibf(g0),au2);
    aup=fmaf(w1,lobf(g1),aup); au2=fmaf(w1,hibf(g1),au2);
    aup=fmaf(w2,lobf(g2),aup); au2=fmaf(w2,hibf(g2),au2);
    aup=fmaf(w3,lobf(g3),aup); au2=fmaf(w3,hibf(g3),au2);
  }
  for (; p < p1; ++p) {
    int j = idx[p]; float v = val[p];
    uint32_t g = qip1[(size_t)j*64 + lane];
    aup = fmaf(v, lobf(g), aup);
    au2 = fmaf(v, hibf(g), au2);
  }
  float m = au2;
#pragma unroll
  for (int o2=32;o2;o2>>=1) m = fmaxf(m, __shfl_xor(m, o2));
  float e = expf(au2 - m);
  float s = e;
#pragma unroll
  for (int o2=32;o2;o2>>=1) s += __shfl_xor(s, o2);
  float u2 = e / s;
  size_t o = (size_t)row*64 + lane;
  up[o] = aup; u2h[o] = f2bf(u2);
  float e0 = idemb[o], e1 = u1[o];
  float v1 = iu[o], v2 = tu[o], v3 = aup, v4 = ufi[o];
  float n1=v1*v1, n2=v2*v2, n3=v3*v3, n4=v4*v4;
#pragma unroll
  for (int o2=32;o2;o2>>=1) {
    n1 += __shfl_xor(n1, o2); n2 += __shfl_xor(n2, o2);
    n3 += __shfl_xor(n3, o2); n4 += __shfl_xor(n4, o2);
  }
  n1 = fmaxf(sqrtf(n1), 1e-12f); n2 = fmaxf(sqrtf(n2), 1e-12f);
  n3 = fmaxf(sqrtf(n3), 1e-12f); n4 = fmaxf(sqrtf(n4), 1e-12f);
  ug[o] = (e0+e1+u2)*(1.f/3.f)
        + 0.02f*(v1/n1) + 0.02f*(v2/n2)
        + 0.30f*(v3/n3) + 0.30f*(v4/n4);
}

__global__ __launch_bounds__(256) void item2_kernel(
    const int* __restrict__ ptr, const int* __restrict__ idx, const float* __restrict__ val,
    const ushort* __restrict__ u2h,
    const float* __restrict__ idemb, const float* __restrict__ i1,
    const float* __restrict__ ii, const float* __restrict__ ti,
    const float* __restrict__ ip, const float* __restrict__ ifo,
    float* __restrict__ ig, int nrows)
{
  int row = blockIdx.x*4 + (threadIdx.x >> 6);
  int lane = threadIdx.x & 63;
  if (row >= nrows) return;
  int p0 = ptr[row], p1 = ptr[row+1];
  float ai2=0.f;
  int p = p0;
  for (; p + 4 <= p1; p += 4) {
    int j0=idx[p+0], j1=idx[p+1], j2=idx[p+2], j3=idx[p+3];
    float w0=val[p+0], w1=val[p+1], w2=val[p+2], w3=val[p+3];
    ushort h0=u2h[(size_t)j0*64+lane], h1=u2h[(size_t)j1*64+lane];
    ushort h2=u2h[(size_t)j2*64+lane], h3=u2h[(size_t)j3*64+lane];
    ai2=fmaf(w0,bf2f(h0),ai2); ai2=fmaf(w1,bf2f(h1),ai2);
    ai2=fmaf(w2,bf2f(h2),ai2); ai2=fmaf(w3,bf2f(h3),ai2);
  }
  for (; p < p1; ++p) {
    int j = idx[p]; float v = val[p];
    ai2 = fmaf(v, bf2f(u2h[(size_t)j*64 + lane]), ai2);
  }
  float m = ai2;
#pragma unroll
  for (int o2=32;o2;o2>>=1) m = fmaxf(m, __shfl_xor(m, o2));
  float e = expf(ai2 - m);
  float s = e;
#pragma unroll
  for (int o2=32;o2;o2>>=1) s += __shfl_xor(s, o2);
  float i2 = e / s;
  size_t o = (size_t)row*64 + lane;
  float e0 = idemb[o], e1 = i1[o];
  float v1 = ii[o], v2 = ti[o], v3 = ip[o], v4 = ifo[o];
  float n1=v1*v1, n2=v2*v2, n3=v3*v3, n4=v4*v4;
#pragma unroll
  for (int o2=32;o2;o2>>=1) {
    n1 += __shfl_xor(n1, o2); n2 += __shfl_xor(n2, o2);
    n3 += __shfl_xor(n3, o2); n4 += __shfl_xor(n4, o2);
  }
  n1 = fmaxf(sqrtf(n1), 1e-12f); n2 = fmaxf(sqrtf(n2), 1e-12f);
  n3 = fmaxf(sqrtf(n3), 1e-12f); n4 = fmaxf(sqrtf(n4), 1e-12f);
  ig[o] = (e0+e1+i2)*(1.f/3.f)
        + 0.02f*(v1/n1) + 0.02f*(v2/n2)
        + 0.30f*(v3/n3) + 0.30f*(v4/n4);
}

// ===================== host =====================
extern "C" void kernel_launch(void* const* d_in, const int* in_sizes, int n_in,
                              void* d_out, int out_size, void* d_ws, size_t ws_size,
                              hipStream_t stream)
{
  const int*   ui_rows     = (const int*)d_in[0];
  const int*   ui_cols     = (const int*)d_in[1];
  const float* ui_vals     = (const float*)d_in[2];
  const float* image_feats = (const float*)d_in[3];
  const float* text_feats  = (const float*)d_in[4];
  const float* user_feats0 = (const float*)d_in[5];
  const float* item_title  = (const float*)d_in[6];
  const float* W_img = (const float*)d_in[7];
  const float* b_img = (const float*)d_in[8];
  const float* W_txt = (const float*)d_in[9];
  const float* b_txt = (const float*)d_in[10];
  const float* W_usr = (const float*)d_in[11];
  const float* b_usr = (const float*)d_in[12];
  const float* W_itm = (const float*)d_in[13];
  const float* b_itm = (const float*)d_in[14];
  const float* user_id_emb = (const float*)d_in[15];
  const float* item_id_emb = (const float*)d_in[16];
  const int nnz = in_sizes[0];

  float* out = (float*)d_out;
  const size_t OU = (size_t)NU*64, OI = (size_t)NI*64;
  size_t off = 0;
  float* o_ug   = out + off; off += OU;
  float* o_ig   = out + off; off += OI;
  float* o_ii   = out + off; off += OI;
  float* o_ti   = out + off; off += OI;
  float* o_iu   = out + off; off += OU;
  float* o_tu   = out + off; off += OU;
  float* o_ue   = out + off; off += OU;
  float* o_ifo  = out + off; off += OI;
  float* o_up   = out + off; off += OU;
  float* o_ip   = out + off; off += OI;
  float* o_ufi  = out + off; off += OU;
  float* o_mask = out + off; off += NMASK;
  float* o_ri   = out + off; off += OI;
  float* o_rt   = out + off; off += OI;
  float* o_rit  = out + off; off += OI;

  char* wp = (char*)d_ws;
  auto walloc = [&](size_t bytes) -> char* {
    char* r = wp; wp += (bytes + 255) & ~(size_t)255; return r;
  };
  // --- zero zone ---
  int*   cnt_u = (int*)  walloc((size_t)NU*4);
  int*   cnt_i = (int*)  walloc((size_t)NI*4);
  int*   flag  = (int*)  walloc((size_t)NI*4);
  float* means = (float*)walloc(3*64*4);
  int*   h1    = (int*)  walloc(NBUCK*4);
  int*   c1    = (int*)  walloc(NBUCK*4);
  int*   h2    = (int*)  walloc(NBUCK*4);
  int*   c2    = (int*)  walloc(NBUCK*4);
  size_t zero_bytes = (size_t)(wp - (char*)d_ws);
  // --- rest ---
  uint32_t* bits1 = (uint32_t*)walloc((size_t)NI*4);
  uint32_t* bits2 = (uint32_t*)walloc((size_t)NI*4);
  uint32_t* permA = (uint32_t*)walloc((size_t)NI*4);
  uint64_t* barr1 = (uint64_t*)walloc((size_t)NI*8);
  uint64_t* barr2 = (uint64_t*)walloc((size_t)NI*8);
  int*   bb1   = (int*)  walloc((NBUCK+1)*4);
  int*   bb2   = (int*)  walloc((NBUCK+1)*4);
  int*   ptr_u = (int*)  walloc((size_t)(NU+1)*4);
  int*   ptr_i = (int*)  walloc((size_t)(NI+1)*4);
  int*   cur_u = (int*)  walloc((size_t)NU*4);
  int*   cur_i = (int*)  walloc((size_t)NI*4);
  int*   idx_u = (int*)  walloc((size_t)nnz*4);
  float* val_u = (float*)walloc((size_t)nnz*4);
  int*   idx_i = (int*)  walloc((size_t)nnz*4);
  float* val_i = (float*)walloc((size_t)nnz*4);
  float* u1    = (float*)walloc(OU*4);
  float* i1    = (float*)walloc(OI*4);
  int*   part_u = (int*) walloc((size_t)NU*4);
  int*   part_i = (int*) walloc((size_t)NI*4);
  int*   bsum_u = (int*) walloc(128*4);
  int*   bsum_i = (int*) walloc(128*4);
  int*   bp_u   = (int*) walloc(129*4);
  int*   bp_i   = (int*) walloc(129*4);
  ushort* wbf  = (ushort*)walloc((size_t)WTOTAL*2);
  uint2* pk_all = (uint2*)walloc(OI*8);
  uint2* q_all  = (uint2*)walloc(OU*8);
  uint32_t* qip1 = (uint32_t*)walloc(OI*4);
  ushort*   ue_bf = (ushort*)walloc(OU*2);
  ushort*   u2h   = (ushort*)walloc(OU*2);
  float* pb_img = (float*)walloc((size_t)8*NI*64*4);
  float* pb_txt = (float*)walloc((size_t)4*NI*64*4);
  float* pb_itm = (float*)walloc((size_t)4*NI*64*4);
  float* pb_usr = (float*)walloc((size_t)6*NU*64*4);
  ushort* wbf_img = wbf;
  ushort* wbf_txt = wbf + 64*4096;
  ushort* wbf_itm = wbf_txt + 64*768;
  ushort* wbf_usr = wbf_itm + 64*1536;

  hipMemsetAsync(d_ws, 0, zero_bytes, stream);

  // --- mask_nodes: exact JAX permutation(key(42), 20000)[:2000] + W->bf16 ---
  const int GB = cdiv(NI,256);
  prep_kernel<<<512, 256, 0, stream>>>(bits1, bits2, h1, h2, W_img, W_txt, W_itm, W_usr, wbf);
  exscan2_kernel<<<2, 64, 0, stream>>>(h1, bb1, h2, bb2);
  scatter12_kernel<<<GB, 256, 0, stream>>>(bits1, bb1, c1, barr1, bits2, bb2, c2, barr2, NI);
  rank_bucket_kernel<0><<<GB, 256, 0, stream>>>(barr1, bb1, permA, nullptr, nullptr, NI);
  rank_bucket_kernel<1><<<GB, 256, 0, stream>>>(barr2, bb2, permA, o_mask, flag, NI);

  // --- raw projections (bf16 MFMA, K-split, separate partial buffers) ---
  {
    dim3 g1(cdiv(NI,64), 8);
    gemm_mfma_kernel<<<g1, 256, 0, stream>>>(image_feats, wbf_img, pb_img, NI, 4096, 512);
    dim3 g2(cdiv(NI,64), 4);
    gemm_mfma_kernel<<<g2, 256, 0, stream>>>(text_feats,  wbf_txt, pb_txt, NI, 768, 192);
    dim3 g3(cdiv(NI,64), 4);
    gemm_mfma_kernel<<<g3, 256, 0, stream>>>(item_title,  wbf_itm, pb_itm, NI, 1536, 384);
    dim3 g4(cdiv(NU,64), 6);
    gemm_mfma_kernel<<<g4, 256, 0, stream>>>(user_feats0, wbf_usr, pb_usr, NU, 1536, 256);
  }
  // one fused reduce: biases, outputs, ue bf16, pk_all pack, column means
  reduce4_kernel<<<512, 256, 0, stream>>>(pb_img, pb_txt, pb_itm, pb_usr,
      b_img, b_txt, b_itm, b_usr, item_id_emb,
      o_ri, o_rt, o_rit, o_ue, ue_bf, pk_all, means);

  // --- CSR build (dual-scan pipeline) ---
  hist_kernel<<<cdiv(nnz,256), 256, 0, stream>>>(ui_rows, ui_cols, cnt_u, cnt_i, nnz);
  {
    int nbu = cdiv(NU,256), nbi = cdiv(NI,256);
    scan_block2_kernel<<<nbu+nbi, 256, 0, stream>>>(cnt_u, cnt_i, part_u, part_i, bsum_u, bsum_i, nbu);
    exscan2b_kernel<<<2, 64, 0, stream>>>(bsum_u, bp_u, nbu, bsum_i, bp_i, nbi);
    scan_add2_kernel<<<nbu+nbi, 256, 0, stream>>>(part_u, bp_u, part_i, bp_i,
        ptr_u, cur_u, ptr_i, cur_i, nbu, nbi);
  }
  scatter_kernel<<<cdiv(nnz,256), 256, 0, stream>>>(ui_rows, ui_cols, ui_vals,
      cur_u, cur_i, idx_u, val_u, idx_i, val_i, nnz);

  const int GU = cdiv(NU,4), GI = cdiv(NI,4);
  spmm_user1_kernel<<<GU,256,0,stream>>>(ptr_u, idx_u, val_u,
      pk_all, flag, means,
      o_iu, o_tu, o_ufi, u1, q_all, NU);
  spmm_item1_kernel<<<GI,256,0,stream>>>(ptr_i, idx_i, val_i,
      q_all, ue_bf,
      o_ii, o_ti, o_ifo, i1, o_ip, qip1, NI);
  user2_kernel<<<GU,256,0,stream>>>(ptr_u, idx_u, val_u,
      qip1, user_id_emb, u1, o_iu, o_tu, o_ufi,
      o_up, u2h, o_ug, NU);
  item2_kernel<<<GI,256,0,stream>>>(ptr_i, idx_i, val_i,
      u2h, item_id_emb, i1, o_ii, o_ti, o_ip, o_ifo,
      o_ig, NI);
}

// Round 12
// 540.075 us; speedup vs baseline: 1.5894x; 1.0704x over previous
//
#include <hip/hip_runtime.h>
#include <hip/hip_bf16.h>
#include <cstdint>
#include <cstddef>

#define NU 30000
#define NI 20000
#define NMASK 2000
#define NBUCK 2048

static inline int cdiv(int a, int b){ return (a + b - 1) / b; }

typedef __attribute__((ext_vector_type(8))) short bf16x8;
typedef __attribute__((ext_vector_type(4))) float f32x4;

// ===================== threefry-2x32 (exact JAX semantics) =====================
__device__ __forceinline__ uint32_t rotl32(uint32_t x, int r){ return (x<<r)|(x>>(32-r)); }

__device__ __forceinline__ void tf2x32(uint32_t k0, uint32_t k1,
                                       uint32_t x0, uint32_t x1,
                                       uint32_t& o0, uint32_t& o1)
{
  uint32_t k2 = k0 ^ k1 ^ 0x1BD11BDAu;
  x0 += k0; x1 += k1;
#define TFR(r) { x0 += x1; x1 = rotl32(x1,(r)); x1 ^= x0; }
  TFR(13) TFR(15) TFR(26) TFR(6)
  x0 += k1; x1 += k2 + 1u;
  TFR(17) TFR(29) TFR(16) TFR(24)
  x0 += k2; x1 += k0 + 2u;
  TFR(13) TFR(15) TFR(26) TFR(6)
  x0 += k0; x1 += k1 + 3u;
  TFR(17) TFR(29) TFR(16) TFR(24)
  x0 += k1; x1 += k2 + 4u;
  TFR(13) TFR(15) TFR(26) TFR(6)
  x0 += k2; x1 += k0 + 5u;
#undef TFR
  o0 = x0; o1 = x1;
}

// ===================== bf16 helpers (HW cvt, RNE) =====================
__device__ __forceinline__ ushort f2bf(float f){
  __hip_bfloat16 h = __float2bfloat16(f);
  return *reinterpret_cast<ushort*>(&h);
}
__device__ __forceinline__ uint32_t pk2(float a, float b){
  __hip_bfloat162 h = __float22bfloat162_rn(make_float2(a, b));
  return *reinterpret_cast<uint32_t*>(&h);
}
__device__ __forceinline__ uint2 f4_to_bf4(float4 v){
  __hip_bfloat162 h0 = __float22bfloat162_rn(make_float2(v.x, v.y));
  __hip_bfloat162 h1 = __float22bfloat162_rn(make_float2(v.z, v.w));
  return make_uint2(*reinterpret_cast<uint32_t*>(&h0), *reinterpret_cast<uint32_t*>(&h1));
}
__device__ __forceinline__ float lobf(uint32_t p){
  union { uint32_t u; float f; } c; c.u = p << 16; return c.f;
}
__device__ __forceinline__ float hibf(uint32_t p){
  union { uint32_t u; float f; } c; c.u = p & 0xffff0000u; return c.f;
}
__device__ __forceinline__ float bf2f(ushort h){
  union { uint32_t u; float f; } c; c.u = (uint32_t)h << 16; return c.f;
}

// ===================== prep: threefry bits + bucket hists + W->bf16 + edge hist =====================
#define WTOTAL (64*(4096+768+1536+1536))
__global__ __launch_bounds__(256) void prep_kernel(
    uint32_t* __restrict__ bits1, uint32_t* __restrict__ bits2,
    int* __restrict__ h1, int* __restrict__ h2,
    const float* __restrict__ wi, const float* __restrict__ wt,
    const float* __restrict__ wm, const float* __restrict__ wu,
    ushort* __restrict__ wbf,
    const int* __restrict__ rows, const int* __restrict__ cols,
    int* __restrict__ cnt_u, int* __restrict__ cnt_i, int nnz)
{
  int i = blockIdx.x*256 + threadIdx.x;
  if (i < NI) {
    uint32_t c0,c1, s0,s1, t0,t1;
    tf2x32(0u,42u, 0u,0u, c0,c1);
    tf2x32(0u,42u, 0u,1u, s0,s1);
    tf2x32(c0,c1, 0u,1u, t0,t1);
    uint32_t o0,o1;
    tf2x32(s0,s1, 0u,(uint32_t)i, o0,o1);
    uint32_t b1 = o0^o1;
    tf2x32(t0,t1, 0u,(uint32_t)i, o0,o1);
    uint32_t b2 = o0^o1;
    bits1[i] = b1; bits2[i] = b2;
    atomicAdd(&h1[b1 >> 21], 1);
    atomicAdd(&h2[b2 >> 21], 1);
  }
  const int n0 = 64*4096, n1 = 64*768, n2 = 64*1536;
  for (int k = i; k < WTOTAL; k += gridDim.x*256) {
    float v;
    if (k < n0) v = wi[k];
    else if (k < n0+n1) v = wt[k-n0];
    else if (k < n0+n1+n2) v = wm[k-n0-n1];
    else v = wu[k-n0-n1-n2];
    wbf[k] = f2bf(v);
  }
  for (int k = i; k < nnz; k += gridDim.x*256) {
    atomicAdd(&cnt_u[rows[k]], 1);
    atomicAdd(&cnt_i[cols[k]], 1);
  }
}

// two independent single-wave exclusive scans over the bucket hists
__global__ __launch_bounds__(64) void exscan2_kernel(
    const int* __restrict__ h1, int* __restrict__ bb1,
    const int* __restrict__ h2, int* __restrict__ bb2)
{
  const int* cnt = blockIdx.x ? h2 : h1;
  int* ptr = blockIdx.x ? bb2 : bb1;
  int lane = threadIdx.x;
  int carry = 0;
  for (int base = 0; base < NBUCK; base += 64) {
    int i = base + lane;
    int v = cnt[i];
    int s = v;
#pragma unroll
    for (int off = 1; off < 64; off <<= 1) {
      int t = __shfl_up(s, off);
      if (lane >= off) s += t;
    }
    ptr[i] = carry + s - v;
    carry += __shfl(s, 63);
  }
  if (lane == 0) ptr[NBUCK] = carry;
}

__global__ __launch_bounds__(256) void scatter12_kernel(
    const uint32_t* __restrict__ bits1, const int* __restrict__ bb1, int* __restrict__ c1,
    uint64_t* __restrict__ barr1,
    const uint32_t* __restrict__ bits2, const int* __restrict__ bb2, int* __restrict__ c2,
    uint64_t* __restrict__ barr2, int n)
{
  int i = blockIdx.x*256 + threadIdx.x;
  if (i >= n) return;
  uint32_t k1 = bits1[i];
  int b = k1 >> 21;
  int p = bb1[b] + atomicAdd(&c1[b], 1);
  barr1[p] = ((uint64_t)k1 << 32) | (uint32_t)i;
  uint32_t k2 = bits2[i];
  b = k2 >> 21;
  p = bb2[b] + atomicAdd(&c2[b], 1);
  barr2[p] = ((uint64_t)k2 << 32) | (uint32_t)i;
}

template<int FINAL>
__global__ __launch_bounds__(256) void rank_bucket_kernel(
    const uint64_t* __restrict__ barr, const int* __restrict__ bptr,
    uint32_t* __restrict__ perm, float* __restrict__ mask_out, int* __restrict__ flag,
    int n)
{
  int p = blockIdx.x*256 + threadIdx.x;
  if (p >= n) return;
  uint64_t mk = barr[p];
  int b = (int)(mk >> 53);
  int p0 = bptr[b], p1 = bptr[b+1];
  int r = p0;
  for (int q = p0; q < p1; ++q) r += (int)(barr[q] < mk);
  uint32_t i = (uint32_t)mk;
  if (!FINAL) {
    perm[r] = i;
  } else if (r < NMASK) {
    uint32_t v = perm[i];
    mask_out[r] = (float)v;
    flag[v] = 1;
  }
}

// ===================== fused MFMA GEMM (all 4 projections in one launch) =====================
// segments: 0=img(313rb x 8ch) 1=txt(313 x 4) 2=itm(313 x 4) 3=usr(469 x 6)
#define RB_I 313
#define RB_U 469
__global__ __launch_bounds__(256) void gemm_all_kernel(
    const float* __restrict__ Xi, const float* __restrict__ Xt,
    const float* __restrict__ Xm, const float* __restrict__ Xu,
    const ushort* __restrict__ wbf,
    ushort* __restrict__ pb_img, ushort* __restrict__ pb_txt,
    ushort* __restrict__ pb_itm, ushort* __restrict__ pb_usr)
{
  __shared__ ushort Xs[64][72];
  __shared__ ushort Ws[64][72];
  const int bid = blockIdx.x;
  const float* X; const ushort* Wbf; ushort* pb;
  int N, K, klen, rb, ch;
  if (bid < RB_I*8) {
    X = Xi; Wbf = wbf; pb = pb_img; N = NI; K = 4096; klen = 512;
    rb = bid % RB_I; ch = bid / RB_I;
  } else if (bid < RB_I*12) {
    int l = bid - RB_I*8;
    X = Xt; Wbf = wbf + 64*4096; pb = pb_txt; N = NI; K = 768; klen = 192;
    rb = l % RB_I; ch = l / RB_I;
  } else if (bid < RB_I*16) {
    int l = bid - RB_I*12;
    X = Xm; Wbf = wbf + 64*(4096+768); pb = pb_itm; N = NI; K = 1536; klen = 384;
    rb = l % RB_I; ch = l / RB_I;
  } else {
    int l = bid - RB_I*16;
    X = Xu; Wbf = wbf + 64*(4096+768+1536); pb = pb_usr; N = NU; K = 1536; klen = 256;
    rb = l % RB_U; ch = l / RB_U;
  }
  const int tid = threadIdx.x;
  const int row0 = rb * 64;
  const int kbeg = ch * klen;
  const int lane = tid & 63;
  const int wr = tid >> 6;
  const int lrow = lane & 15;
  const int kslot = lane >> 4;
  f32x4 acc[4] = {f32x4{0,0,0,0},f32x4{0,0,0,0},f32x4{0,0,0,0},f32x4{0,0,0,0}};

  const int sr = tid >> 4;
  const int sc = (tid & 15) * 4;
  const int wrow = tid >> 2;
  const int wcol = (tid & 3) * 16;

  for (int k0 = kbeg; k0 < kbeg + klen; k0 += 64) {
#pragma unroll
    for (int i = 0; i < 4; ++i) {
      int r = sr + 16*i;
      int gr = row0 + r;
      float4 v = make_float4(0.f,0.f,0.f,0.f);
      if (gr < N) v = *reinterpret_cast<const float4*>(X + (size_t)gr*K + k0 + sc);
      *reinterpret_cast<uint2*>(&Xs[r][sc]) = f4_to_bf4(v);
    }
    {
      const ushort* wsrc = Wbf + (size_t)wrow*K + k0 + wcol;
      *reinterpret_cast<uint4*>(&Ws[wrow][wcol])   = *reinterpret_cast<const uint4*>(wsrc);
      *reinterpret_cast<uint4*>(&Ws[wrow][wcol+8]) = *reinterpret_cast<const uint4*>(wsrc + 8);
    }
    __syncthreads();
#pragma unroll
    for (int ks = 0; ks < 2; ++ks) {
      int kb = ks*32 + kslot*8;
      bf16x8 af = *reinterpret_cast<const bf16x8*>(&Xs[wr*16 + lrow][kb]);
#pragma unroll
      for (int ct = 0; ct < 4; ++ct) {
        bf16x8 bfr = *reinterpret_cast<const bf16x8*>(&Ws[ct*16 + lrow][kb]);
        acc[ct] = __builtin_amdgcn_mfma_f32_16x16x32_bf16(af, bfr, acc[ct], 0, 0, 0);
      }
    }
    __syncthreads();
  }
  ushort* pbc = pb + (size_t)ch * N * 64;
#pragma unroll
  for (int ct = 0; ct < 4; ++ct)
#pragma unroll
    for (int j = 0; j < 4; ++j) {
      int gr = row0 + wr*16 + kslot*4 + j;
      if (gr < N) pbc[(size_t)gr*64 + ct*16 + lrow] = f2bf(acc[ct][j]);
    }
}

// ===================== fused reduce for all 4 GEMMs + pack + column means =====================
__global__ __launch_bounds__(256) void reduce4_kernel(
    const ushort* __restrict__ pb_img, const ushort* __restrict__ pb_txt,
    const ushort* __restrict__ pb_itm, const ushort* __restrict__ pb_usr,
    const float* __restrict__ b_img, const float* __restrict__ b_txt,
    const float* __restrict__ b_itm, const float* __restrict__ b_usr,
    const float* __restrict__ idemb,
    float* __restrict__ o_ri, float* __restrict__ o_rt, float* __restrict__ o_rit,
    float* __restrict__ o_ue, ushort* __restrict__ ue_bf,
    uint2* __restrict__ pk_all, float* __restrict__ means)
{
  __shared__ float red[3][256];
  const int nI = NI*64, nUx = NU*64;
  int lane = threadIdx.x & 63;
  float sa = 0.f, sb = 0.f, sc = 0.f;
  for (int i = blockIdx.x*256 + threadIdx.x; i < nUx; i += gridDim.x*256) {
    int lc = i & 63;
    if (i < nI) {
      float s = b_img[lc];
#pragma unroll
      for (int c = 0; c < 8; ++c) s += bf2f(pb_img[(size_t)c*nI + i]);
      o_ri[i] = s;
      float t = b_txt[lc];
#pragma unroll
      for (int c = 0; c < 4; ++c) t += bf2f(pb_txt[(size_t)c*nI + i]);
      o_rt[i] = t;
      float u = b_itm[lc];
#pragma unroll
      for (int c = 0; c < 4; ++c) u += bf2f(pb_itm[(size_t)c*nI + i]);
      o_rit[i] = u;
      pk_all[i] = make_uint2(pk2(s, t), pk2(u, idemb[i]));
      sa += s; sb += t; sc += u;
    }
    float su = b_usr[lc];
#pragma unroll
    for (int c = 0; c < 6; ++c) su += bf2f(pb_usr[(size_t)c*nUx + i]);
    o_ue[i] = su; ue_bf[i] = f2bf(su);
  }
  red[0][threadIdx.x] = sa; red[1][threadIdx.x] = sb; red[2][threadIdx.x] = sc;
  __syncthreads();
  if (threadIdx.x < 64) {
#pragma unroll
    for (int q = 0; q < 3; ++q) {
      float t = red[q][lane]+red[q][64+lane]+red[q][128+lane]+red[q][192+lane];
      if (t != 0.f) atomicAdd(&means[q*64+lane], t * (1.f/NI));
    }
  }
}

// ===================== CSR build (dual-scan) =====================
__global__ __launch_bounds__(256) void scan_block2_kernel(
    const int* __restrict__ cnt_u, const int* __restrict__ cnt_i,
    int* __restrict__ part_u, int* __restrict__ part_i,
    int* __restrict__ bsum_u, int* __restrict__ bsum_i, int nbu)
{
  __shared__ int wsum[4];
  bool isU = (int)blockIdx.x < nbu;
  int blk = isU ? blockIdx.x : blockIdx.x - nbu;
  const int* cnt = isU ? cnt_u : cnt_i;
  int* part = isU ? part_u : part_i;
  int* bsum = isU ? bsum_u : bsum_i;
  int n = isU ? NU : NI;
  int i = blk*256 + threadIdx.x;
  int lane = threadIdx.x & 63;
  int w = threadIdx.x >> 6;
  int v = (i < n) ? cnt[i] : 0;
  int s = v;
#pragma unroll
  for (int off = 1; off < 64; off <<= 1) {
    int t = __shfl_up(s, off);
    if (lane >= off) s += t;
  }
  if (lane == 63) wsum[w] = s;
  __syncthreads();
  int wo = 0;
#pragma unroll
  for (int k = 0; k < 4; ++k) if (k < w) wo += wsum[k];
  if (i < n) part[i] = wo + s - v;
  if (threadIdx.x == 255) bsum[blk] = wo + s;
}

__global__ __launch_bounds__(64) void exscan2b_kernel(
    const int* __restrict__ bs_u, int* __restrict__ bp_u, int nbu,
    const int* __restrict__ bs_i, int* __restrict__ bp_i, int nbi)
{
  const int* cnt = blockIdx.x ? bs_i : bs_u;
  int* ptr = blockIdx.x ? bp_i : bp_u;
  int n = blockIdx.x ? nbi : nbu;
  int lane = threadIdx.x;
  int carry = 0;
  for (int base = 0; base < n; base += 64) {
    int i = base + lane;
    int v = (i < n) ? cnt[i] : 0;
    int s = v;
#pragma unroll
    for (int off = 1; off < 64; off <<= 1) {
      int t = __shfl_up(s, off);
      if (lane >= off) s += t;
    }
    if (i < n) ptr[i] = carry + s - v;
    carry += __shfl(s, 63);
  }
  if (lane == 0) ptr[n] = carry;
}

__global__ __launch_bounds__(256) void scan_add2_kernel(
    const int* __restrict__ part_u, const int* __restrict__ bp_u,
    const int* __restrict__ part_i, const int* __restrict__ bp_i,
    int* __restrict__ ptr_u, int* __restrict__ cur_u,
    int* __restrict__ ptr_i, int* __restrict__ cur_i, int nbu, int nbi)
{
  bool isU = (int)blockIdx.x < nbu;
  int blk = isU ? blockIdx.x : blockIdx.x - nbu;
  int n = isU ? NU : NI;
  const int* part = isU ? part_u : part_i;
  const int* bp = isU ? bp_u : bp_i;
  int* ptr = isU ? ptr_u : ptr_i;
  int* cur = isU ? cur_u : cur_i;
  int i = blk*256 + threadIdx.x;
  if (i < n) { int v = part[i] + bp[blk]; ptr[i] = v; cur[i] = v; }
  if (i == 0) ptr[n] = bp[isU ? nbu : nbi];
}

__global__ __launch_bounds__(256) void scatter_kernel(
    const int* __restrict__ rows, const int* __restrict__ cols, const float* __restrict__ vals,
    int* __restrict__ cur_u, int* __restrict__ cur_i,
    int* __restrict__ idx_u, float* __restrict__ val_u,
    int* __restrict__ idx_i, float* __restrict__ val_i, int nnz)
{
  int k = blockIdx.x*256 + threadIdx.x;
  if (k < nnz) {
    int r = rows[k], c = cols[k];
    float v = vals[k];
    int pu = atomicAdd(&cur_u[r], 1);
    idx_u[pu] = c; val_u[pu] = v;
    int pi = atomicAdd(&cur_i[c], 1);
    idx_i[pi] = r; val_i[pi] = v;
  }
}

// ===================== fused SpMMs (uint2 bf16 gathers, 8/4/1 cascade unroll) =====================
__global__ __launch_bounds__(256) void spmm_user1_kernel(
    const int* __restrict__ ptr, const int* __restrict__ idx, const float* __restrict__ val,
    const uint2* __restrict__ pka,
    const int* __restrict__ flag, const float* __restrict__ means,
    float* __restrict__ iu, float* __restrict__ tu, float* __restrict__ ufi, float* __restrict__ u1,
    uint2* __restrict__ qa, int nrows)
{
  int row = blockIdx.x*4 + (threadIdx.x >> 6);
  int lane = threadIdx.x & 63;
  if (row >= nrows) return;
  int p0 = ptr[row], p1 = ptr[row+1];
  float m0 = means[lane], m1 = means[64+lane], m2 = means[128+lane];
  float a0=0.f, a1=0.f, a2=0.f, a3=0.f;
#define U1STEP(gg,ff,ww) { float x0,x1,x2, x3 = hibf(gg.y); \
    if (ff) { x0=m0; x1=m1; x2=m2; } \
    else { x0=lobf(gg.x); x1=hibf(gg.x); x2=lobf(gg.y); } \
    a0=fmaf(ww,x0,a0); a1=fmaf(ww,x1,a1); a2=fmaf(ww,x2,a2); a3=fmaf(ww,x3,a3); }
  int p = p0;
  for (; p + 8 <= p1; p += 8) {
    int j[8]; float w[8]; int f[8]; uint2 g[8];
#pragma unroll
    for (int q = 0; q < 8; ++q) { j[q]=idx[p+q]; w[q]=val[p+q]; }
#pragma unroll
    for (int q = 0; q < 8; ++q) { f[q]=flag[j[q]]; g[q]=pka[(size_t)j[q]*64+lane]; }
#pragma unroll
    for (int q = 0; q < 8; ++q) U1STEP(g[q],f[q],w[q])
  }
  for (; p + 4 <= p1; p += 4) {
    int j0=idx[p+0], j1=idx[p+1], j2=idx[p+2], j3=idx[p+3];
    float w0=val[p+0], w1=val[p+1], w2=val[p+2], w3=val[p+3];
    int f0=flag[j0], f1=flag[j1], f2=flag[j2], f3=flag[j3];
    uint2 g0=pka[(size_t)j0*64+lane], g1=pka[(size_t)j1*64+lane];
    uint2 g2=pka[(size_t)j2*64+lane], g3=pka[(size_t)j3*64+lane];
    U1STEP(g0,f0,w0) U1STEP(g1,f1,w1) U1STEP(g2,f2,w2) U1STEP(g3,f3,w3)
  }
  for (; p < p1; ++p) {
    int j = idx[p]; float v = val[p];
    uint2 g = pka[(size_t)j*64 + lane];
    int f = flag[j];
    U1STEP(g,f,v)
  }
#undef U1STEP
  size_t o = (size_t)row*64 + lane;
  iu[o]=a0; tu[o]=a1; ufi[o]=a2; u1[o]=a3;
  qa[o] = make_uint2(pk2(a0, a1), pk2(a2, a3));
}

__global__ __launch_bounds__(256) void spmm_item1_kernel(
    const int* __restrict__ ptr, const int* __restrict__ idx, const float* __restrict__ val,
    const uint2* __restrict__ qa, const ushort* __restrict__ ueh,
    float* __restrict__ ii, float* __restrict__ ti, float* __restrict__ ifo,
    float* __restrict__ i1, float* __restrict__ ip,
    uint32_t* __restrict__ qip1, int nrows)
{
  int row = blockIdx.x*4 + (threadIdx.x >> 6);
  int lane = threadIdx.x & 63;
  if (row >= nrows) return;
  int p0 = ptr[row], p1 = ptr[row+1];
  float a0=0.f, a1=0.f, a2=0.f, a3=0.f, a4=0.f;
#define I1STEP(gg,uu,ww) { \
    a0=fmaf(ww,lobf(gg.x),a0); a1=fmaf(ww,hibf(gg.x),a1); \
    a2=fmaf(ww,lobf(gg.y),a2); a3=fmaf(ww,hibf(gg.y),a3); \
    a4=fmaf(ww,bf2f(uu),a4); }
  int p = p0;
  for (; p + 8 <= p1; p += 8) {
    int j[8]; float w[8]; uint2 g[8]; ushort u[8];
#pragma unroll
    for (int q = 0; q < 8; ++q) { j[q]=idx[p+q]; w[q]=val[p+q]; }
#pragma unroll
    for (int q = 0; q < 8; ++q) {
      size_t b = (size_t)j[q]*64+lane;
      g[q]=qa[b]; u[q]=ueh[b];
    }
#pragma unroll
    for (int q = 0; q < 8; ++q) I1STEP(g[q],u[q],w[q])
  }
  for (; p + 4 <= p1; p += 4) {
    int j0=idx[p+0], j1=idx[p+1], j2=idx[p+2], j3=idx[p+3];
    float w0=val[p+0], w1=val[p+1], w2=val[p+2], w3=val[p+3];
    size_t b0=(size_t)j0*64+lane, b1=(size_t)j1*64+lane, b2=(size_t)j2*64+lane, b3=(size_t)j3*64+lane;
    uint2 g0=qa[b0], g1=qa[b1], g2=qa[b2], g3=qa[b3];
    ushort u0=ueh[b0], u1_=ueh[b1], u2_=ueh[b2], u3_=ueh[b3];
    I1STEP(g0,u0,w0) I1STEP(g1,u1_,w1) I1STEP(g2,u2_,w2) I1STEP(g3,u3_,w3)
  }
  for (; p < p1; ++p) {
    int j = idx[p]; float v = val[p];
    size_t b = (size_t)j*64 + lane;
    uint2 g = qa[b]; ushort u = ueh[b];
    I1STEP(g,u,v)
  }
#undef I1STEP
  size_t o = (size_t)row*64 + lane;
  ii[o]=a0; ti[o]=a1; ifo[o]=a2; i1[o]=a3; ip[o]=a4;
  qip1[o] = pk2(a4, a3);
}

__global__ __launch_bounds__(256) void user2_kernel(
    const int* __restrict__ ptr, const int* __restrict__ idx, const float* __restrict__ val,
    const uint32_t* __restrict__ qip1,
    const float* __restrict__ idemb, const float* __restrict__ u1,
    const float* __restrict__ iu, const float* __restrict__ tu, const float* __restrict__ ufi,
    float* __restrict__ up, ushort* __restrict__ u2h, float* __restrict__ ug, int nrows)
{
  int row = blockIdx.x*4 + (threadIdx.x >> 6);
  int lane = threadIdx.x & 63;
  if (row >= nrows) return;
  int p0 = ptr[row], p1 = ptr[row+1];
  float aup=0.f, au2=0.f;
  int p = p0;
  for (; p + 4 <= p1; p += 4) {
    int j0=idx[p+0], j1=idx[p+1], j2=idx[p+2], j3=idx[p+3];
    float w0=val[p+0], w1=val[p+1], w2=val[p+2], w3=val[p+3];
    uint32_t g0=qip1[(size_t)j0*64+lane], g1=qip1[(size_t)j1*64+lane];
    uint32_t g2=qip1[(size_t)j2*64+lane], g3=qip1[(size_t)j3*64+lane];
    aup=fmaf(w0,lobf(g0),aup); au2=fmaf(w0,hibf(g0),au2);
    aup=fmaf(w1,lobf(g1),aup); au2=fmaf(w1,hibf(g1),au2);
    aup=fmaf(w2,lobf(g2),aup); au2=fmaf(w2,hibf(g2),au2);
    aup=fmaf(w3,lobf(g3),aup); au2=fmaf(w3,hibf(g3),au2);
  }
  for (; p < p1; ++p) {
    int j = idx[p]; float v = val[p];
    uint32_t g = qip1[(size_t)j*64 + lane];
    aup = fmaf(v, lobf(g), aup);
    au2 = fmaf(v, hibf(g), au2);
  }
  float m = au2;
#pragma unroll
  for (int o2=32;o2;o2>>=1) m = fmaxf(m, __shfl_xor(m, o2));
  float e = expf(au2 - m);
  float s = e;
#pragma unroll
  for (int o2=32;o2;o2>>=1) s += __shfl_xor(s, o2);
  float u2 = e / s;
  size_t o = (size_t)row*64 + lane;
  up[o] = aup; u2h[o] = f2bf(u2);
  float e0 = idemb[o], e1 = u1[o];
  float v1 = iu[o], v2 = tu[o], v3 = aup, v4 = ufi[o];
  float n1=v1*v1, n2=v2*v2, n3=v3*v3, n4=v4*v4;
#pragma unroll
  for (int o2=32;o2;o2>>=1) {
    n1 += __shfl_xor(n1, o2); n2 += __shfl_xor(n2, o2);
    n3 += __shfl_xor(n3, o2); n4 += __shfl_xor(n4, o2);
  }
  n1 = fmaxf(sqrtf(n1), 1e-12f); n2 = fmaxf(sqrtf(n2), 1e-12f);
  n3 = fmaxf(sqrtf(n3), 1e-12f); n4 = fmaxf(sqrtf(n4), 1e-12f);
  ug[o] = (e0+e1+u2)*(1.f/3.f)
        + 0.02f*(v1/n1) + 0.02f*(v2/n2)
        + 0.30f*(v3/n3) + 0.30f*(v4/n4);
}

__global__ __launch_bounds__(256) void item2_kernel(
    const int* __restrict__ ptr, const int* __restrict__ idx, const float* __restrict__ val,
    const ushort* __restrict__ u2h,
    const float* __restrict__ idemb, const float* __restrict__ i1,
    const float* __restrict__ ii, const float* __restrict__ ti,
    const float* __restrict__ ip, const float* __restrict__ ifo,
    float* __restrict__ ig, int nrows)
{
  int row = blockIdx.x*4 + (threadIdx.x >> 6);
  int lane = threadIdx.x & 63;
  if (row >= nrows) return;
  int p0 = ptr[row], p1 = ptr[row+1];
  float ai2=0.f;
  int p = p0;
  for (; p + 4 <= p1; p += 4) {
    int j0=idx[p+0], j1=idx[p+1], j2=idx[p+2], j3=idx[p+3];
    float w0=val[p+0], w1=val[p+1], w2=val[p+2], w3=val[p+3];
    ushort h0=u2h[(size_t)j0*64+lane], h1=u2h[(size_t)j1*64+lane];
    ushort h2=u2h[(size_t)j2*64+lane], h3=u2h[(size_t)j3*64+lane];
    ai2=fmaf(w0,bf2f(h0),ai2); ai2=fmaf(w1,bf2f(h1),ai2);
    ai2=fmaf(w2,bf2f(h2),ai2); ai2=fmaf(w3,bf2f(h3),ai2);
  }
  for (; p < p1; ++p) {
    int j = idx[p]; float v = val[p];
    ai2 = fmaf(v, bf2f(u2h[(size_t)j*64 + lane]), ai2);
  }
  float m = ai2;
#pragma unroll
  for (int o2=32;o2;o2>>=1) m = fmaxf(m, __shfl_xor(m, o2));
  float e = expf(ai2 - m);
  float s = e;
#pragma unroll
  for (int o2=32;o2;o2>>=1) s += __shfl_xor(s, o2);
  float i2 = e / s;
  size_t o = (size_t)row*64 + lane;
  float e0 = idemb[o], e1 = i1[o];
  float v1 = ii[o], v2 = ti[o], v3 = ip[o], v4 = ifo[o];
  float n1=v1*v1, n2=v2*v2, n3=v3*v3, n4=v4*v4;
#pragma unroll
  for (int o2=32;o2;o2>>=1) {
    n1 += __shfl_xor(n1, o2); n2 += __shfl_xor(n2, o2);
    n3 += __shfl_xor(n3, o2); n4 += __shfl_xor(n4, o2);
  }
  n1 = fmaxf(sqrtf(n1), 1e-12f); n2 = fmaxf(sqrtf(n2), 1e-12f);
  n3 = fmaxf(sqrtf(n3), 1e-12f); n4 = fmaxf(sqrtf(n4), 1e-12f);
  ig[o] = (e0+e1+i2)*(1.f/3.f)
        + 0.02f*(v1/n1) + 0.02f*(v2/n2)
        + 0.30f*(v3/n3) + 0.30f*(v4/n4);
}

// ===================== host =====================
extern "C" void kernel_launch(void* const* d_in, const int* in_sizes, int n_in,
                              void* d_out, int out_size, void* d_ws, size_t ws_size,
                              hipStream_t stream)
{
  const int*   ui_rows     = (const int*)d_in[0];
  const int*   ui_cols     = (const int*)d_in[1];
  const float* ui_vals     = (const float*)d_in[2];
  const float* image_feats = (const float*)d_in[3];
  const float* text_feats  = (const float*)d_in[4];
  const float* user_feats0 = (const float*)d_in[5];
  const float* item_title  = (const float*)d_in[6];
  const float* W_img = (const float*)d_in[7];
  const float* b_img = (const float*)d_in[8];
  const float* W_txt = (const float*)d_in[9];
  const float* b_txt = (const float*)d_in[10];
  const float* W_usr = (const float*)d_in[11];
  const float* b_usr = (const float*)d_in[12];
  const float* W_itm = (const float*)d_in[13];
  const float* b_itm = (const float*)d_in[14];
  const float* user_id_emb = (const float*)d_in[15];
  const float* item_id_emb = (const float*)d_in[16];
  const int nnz = in_sizes[0];

  float* out = (float*)d_out;
  const size_t OU = (size_t)NU*64, OI = (size_t)NI*64;
  size_t off = 0;
  float* o_ug   = out + off; off += OU;
  float* o_ig   = out + off; off += OI;
  float* o_ii   = out + off; off += OI;
  float* o_ti   = out + off; off += OI;
  float* o_iu   = out + off; off += OU;
  float* o_tu   = out + off; off += OU;
  float* o_ue   = out + off; off += OU;
  float* o_ifo  = out + off; off += OI;
  float* o_up   = out + off; off += OU;
  float* o_ip   = out + off; off += OI;
  float* o_ufi  = out + off; off += OU;
  float* o_mask = out + off; off += NMASK;
  float* o_ri   = out + off; off += OI;
  float* o_rt   = out + off; off += OI;
  float* o_rit  = out + off; off += OI;

  char* wp = (char*)d_ws;
  auto walloc = [&](size_t bytes) -> char* {
    char* r = wp; wp += (bytes + 255) & ~(size_t)255; return r;
  };
  // --- zero zone ---
  int*   cnt_u = (int*)  walloc((size_t)NU*4);
  int*   cnt_i = (int*)  walloc((size_t)NI*4);
  int*   flag  = (int*)  walloc((size_t)NI*4);
  float* means = (float*)walloc(3*64*4);
  int*   h1    = (int*)  walloc(NBUCK*4);
  int*   c1    = (int*)  walloc(NBUCK*4);
  int*   h2    = (int*)  walloc(NBUCK*4);
  int*   c2    = (int*)  walloc(NBUCK*4);
  size_t zero_bytes = (size_t)(wp - (char*)d_ws);
  // --- rest ---
  uint32_t* bits1 = (uint32_t*)walloc((size_t)NI*4);
  uint32_t* bits2 = (uint32_t*)walloc((size_t)NI*4);
  uint32_t* permA = (uint32_t*)walloc((size_t)NI*4);
  uint64_t* barr1 = (uint64_t*)walloc((size_t)NI*8);
  uint64_t* barr2 = (uint64_t*)walloc((size_t)NI*8);
  int*   bb1   = (int*)  walloc((NBUCK+1)*4);
  int*   bb2   = (int*)  walloc((NBUCK+1)*4);
  int*   ptr_u = (int*)  walloc((size_t)(NU+1)*4);
  int*   ptr_i = (int*)  walloc((size_t)(NI+1)*4);
  int*   cur_u = (int*)  walloc((size_t)NU*4);
  int*   cur_i = (int*)  walloc((size_t)NI*4);
  int*   idx_u = (int*)  walloc((size_t)nnz*4);
  float* val_u = (float*)walloc((size_t)nnz*4);
  int*   idx_i = (int*)  walloc((size_t)nnz*4);
  float* val_i = (float*)walloc((size_t)nnz*4);
  float* u1    = (float*)walloc(OU*4);
  float* i1    = (float*)walloc(OI*4);
  int*   part_u = (int*) walloc((size_t)NU*4);
  int*   part_i = (int*) walloc((size_t)NI*4);
  int*   bsum_u = (int*) walloc(128*4);
  int*   bsum_i = (int*) walloc(128*4);
  int*   bp_u   = (int*) walloc(129*4);
  int*   bp_i   = (int*) walloc(129*4);
  ushort* wbf  = (ushort*)walloc((size_t)WTOTAL*2);
  uint2* pk_all = (uint2*)walloc(OI*8);
  uint2* q_all  = (uint2*)walloc(OU*8);
  uint32_t* qip1 = (uint32_t*)walloc(OI*4);
  ushort*   ue_bf = (ushort*)walloc(OU*2);
  ushort*   u2h   = (ushort*)walloc(OU*2);
  ushort* pb_img = (ushort*)walloc((size_t)8*NI*64*2);
  ushort* pb_txt = (ushort*)walloc((size_t)4*NI*64*2);
  ushort* pb_itm = (ushort*)walloc((size_t)4*NI*64*2);
  ushort* pb_usr = (ushort*)walloc((size_t)6*NU*64*2);

  hipMemsetAsync(d_ws, 0, zero_bytes, stream);

  // --- prep: threefry + W->bf16 + edge histogram (one launch) ---
  prep_kernel<<<512, 256, 0, stream>>>(bits1, bits2, h1, h2,
      W_img, W_txt, W_itm, W_usr, wbf, ui_rows, ui_cols, cnt_u, cnt_i, nnz);

  // --- mask_nodes: bucketed stable sorts ---
  const int GB = cdiv(NI,256);
  exscan2_kernel<<<2, 64, 0, stream>>>(h1, bb1, h2, bb2);
  scatter12_kernel<<<GB, 256, 0, stream>>>(bits1, bb1, c1, barr1, bits2, bb2, c2, barr2, NI);
  rank_bucket_kernel<0><<<GB, 256, 0, stream>>>(barr1, bb1, permA, nullptr, nullptr, NI);
  rank_bucket_kernel<1><<<GB, 256, 0, stream>>>(barr2, bb2, permA, o_mask, flag, NI);

  // --- all 4 projections in one launch (bf16 MFMA, K-split, bf16 partials) ---
  gemm_all_kernel<<<RB_I*16 + RB_U*6, 256, 0, stream>>>(
      image_feats, text_feats, item_title, user_feats0, wbf,
      pb_img, pb_txt, pb_itm, pb_usr);
  reduce4_kernel<<<1024, 256, 0, stream>>>(pb_img, pb_txt, pb_itm, pb_usr,
      b_img, b_txt, b_itm, b_usr, item_id_emb,
      o_ri, o_rt, o_rit, o_ue, ue_bf, pk_all, means);

  // --- CSR build (dual-scan pipeline; hist already done in prep) ---
  {
    int nbu = cdiv(NU,256), nbi = cdiv(NI,256);
    scan_block2_kernel<<<nbu+nbi, 256, 0, stream>>>(cnt_u, cnt_i, part_u, part_i, bsum_u, bsum_i, nbu);
    exscan2b_kernel<<<2, 64, 0, stream>>>(bsum_u, bp_u, nbu, bsum_i, bp_i, nbi);
    scan_add2_kernel<<<nbu+nbi, 256, 0, stream>>>(part_u, bp_u, part_i, bp_i,
        ptr_u, cur_u, ptr_i, cur_i, nbu, nbi);
  }
  scatter_kernel<<<cdiv(nnz,256), 256, 0, stream>>>(ui_rows, ui_cols, ui_vals,
      cur_u, cur_i, idx_u, val_u, idx_i, val_i, nnz);

  const int GU = cdiv(NU,4), GI = cdiv(NI,4);
  spmm_user1_kernel<<<GU,256,0,stream>>>(ptr_u, idx_u, val_u,
      pk_all, flag, means,
      o_iu, o_tu, o_ufi, u1, q_all, NU);
  spmm_item1_kernel<<<GI,256,0,stream>>>(ptr_i, idx_i, val_i,
      q_all, ue_bf,
      o_ii, o_ti, o_ifo, i1, o_ip, qip1, NI);
  user2_kernel<<<GU,256,0,stream>>>(ptr_u, idx_u, val_u,
      qip1, user_id_emb, u1, o_iu, o_tu, o_ufi,
      o_up, u2h, o_ug, NU);
  item2_kernel<<<GI,256,0,stream>>>(ptr_i, idx_i, val_i,
      u2h, item_id_emb, i1, o_ii, o_ti, o_ip, o_ifo,
      o_ig, NI);
}

// Round 13
// 531.933 us; speedup vs baseline: 1.6138x; 1.0153x over previous
//
#include <hip/hip_runtime.h>
#include <hip/hip_bf16.h>
#include <cstdint>
#include <cstddef>

#define NU 30000
#define NI 20000
#define NMASK 2000
#define NBUCK 2048

static inline int cdiv(int a, int b){ return (a + b - 1) / b; }

typedef __attribute__((ext_vector_type(8))) short bf16x8;
typedef __attribute__((ext_vector_type(4))) float f32x4;

// ===================== threefry-2x32 (exact JAX semantics) =====================
__device__ __forceinline__ uint32_t rotl32(uint32_t x, int r){ return (x<<r)|(x>>(32-r)); }

__device__ __forceinline__ void tf2x32(uint32_t k0, uint32_t k1,
                                       uint32_t x0, uint32_t x1,
                                       uint32_t& o0, uint32_t& o1)
{
  uint32_t k2 = k0 ^ k1 ^ 0x1BD11BDAu;
  x0 += k0; x1 += k1;
#define TFR(r) { x0 += x1; x1 = rotl32(x1,(r)); x1 ^= x0; }
  TFR(13) TFR(15) TFR(26) TFR(6)
  x0 += k1; x1 += k2 + 1u;
  TFR(17) TFR(29) TFR(16) TFR(24)
  x0 += k2; x1 += k0 + 2u;
  TFR(13) TFR(15) TFR(26) TFR(6)
  x0 += k0; x1 += k1 + 3u;
  TFR(17) TFR(29) TFR(16) TFR(24)
  x0 += k1; x1 += k2 + 4u;
  TFR(13) TFR(15) TFR(26) TFR(6)
  x0 += k2; x1 += k0 + 5u;
#undef TFR
  o0 = x0; o1 = x1;
}

// ===================== bf16 helpers (HW cvt, RNE) =====================
__device__ __forceinline__ ushort f2bf(float f){
  __hip_bfloat16 h = __float2bfloat16(f);
  return *reinterpret_cast<ushort*>(&h);
}
__device__ __forceinline__ uint32_t pk2(float a, float b){
  __hip_bfloat162 h = __float22bfloat162_rn(make_float2(a, b));
  return *reinterpret_cast<uint32_t*>(&h);
}
__device__ __forceinline__ uint2 f4_to_bf4(float4 v){
  __hip_bfloat162 h0 = __float22bfloat162_rn(make_float2(v.x, v.y));
  __hip_bfloat162 h1 = __float22bfloat162_rn(make_float2(v.z, v.w));
  return make_uint2(*reinterpret_cast<uint32_t*>(&h0), *reinterpret_cast<uint32_t*>(&h1));
}
__device__ __forceinline__ float lobf(uint32_t p){
  union { uint32_t u; float f; } c; c.u = p << 16; return c.f;
}
__device__ __forceinline__ float hibf(uint32_t p){
  union { uint32_t u; float f; } c; c.u = p & 0xffff0000u; return c.f;
}
__device__ __forceinline__ float bf2f(ushort h){
  union { uint32_t u; float f; } c; c.u = (uint32_t)h << 16; return c.f;
}

// ===================== prep: threefry bits + bucket hists + W->bf16 + edge hist =====================
#define WTOTAL (64*(4096+768+1536+1536))
__global__ __launch_bounds__(256) void prep_kernel(
    uint32_t* __restrict__ bits1, uint32_t* __restrict__ bits2,
    int* __restrict__ h1, int* __restrict__ h2,
    const float* __restrict__ wi, const float* __restrict__ wt,
    const float* __restrict__ wm, const float* __restrict__ wu,
    ushort* __restrict__ wbf,
    const int* __restrict__ rows, const int* __restrict__ cols,
    int* __restrict__ cnt_u, int* __restrict__ cnt_i, int nnz)
{
  int i = blockIdx.x*256 + threadIdx.x;
  if (i < NI) {
    uint32_t c0,c1, s0,s1, t0,t1;
    tf2x32(0u,42u, 0u,0u, c0,c1);
    tf2x32(0u,42u, 0u,1u, s0,s1);
    tf2x32(c0,c1, 0u,1u, t0,t1);
    uint32_t o0,o1;
    tf2x32(s0,s1, 0u,(uint32_t)i, o0,o1);
    uint32_t b1 = o0^o1;
    tf2x32(t0,t1, 0u,(uint32_t)i, o0,o1);
    uint32_t b2 = o0^o1;
    bits1[i] = b1; bits2[i] = b2;
    atomicAdd(&h1[b1 >> 21], 1);
    atomicAdd(&h2[b2 >> 21], 1);
  }
  const int n0 = 64*4096, n1 = 64*768, n2 = 64*1536;
  for (int k = i; k < WTOTAL; k += gridDim.x*256) {
    float v;
    if (k < n0) v = wi[k];
    else if (k < n0+n1) v = wt[k-n0];
    else if (k < n0+n1+n2) v = wm[k-n0-n1];
    else v = wu[k-n0-n1-n2];
    wbf[k] = f2bf(v);
  }
  for (int k = i; k < nnz; k += gridDim.x*256) {
    atomicAdd(&cnt_u[rows[k]], 1);
    atomicAdd(&cnt_i[cols[k]], 1);
  }
}

// two independent single-wave exclusive scans over the bucket hists
__global__ __launch_bounds__(64) void exscan2_kernel(
    const int* __restrict__ h1, int* __restrict__ bb1,
    const int* __restrict__ h2, int* __restrict__ bb2)
{
  const int* cnt = blockIdx.x ? h2 : h1;
  int* ptr = blockIdx.x ? bb2 : bb1;
  int lane = threadIdx.x;
  int carry = 0;
  for (int base = 0; base < NBUCK; base += 64) {
    int i = base + lane;
    int v = cnt[i];
    int s = v;
#pragma unroll
    for (int off = 1; off < 64; off <<= 1) {
      int t = __shfl_up(s, off);
      if (lane >= off) s += t;
    }
    ptr[i] = carry + s - v;
    carry += __shfl(s, 63);
  }
  if (lane == 0) ptr[NBUCK] = carry;
}

__global__ __launch_bounds__(256) void scatter12_kernel(
    const uint32_t* __restrict__ bits1, const int* __restrict__ bb1, int* __restrict__ c1,
    uint64_t* __restrict__ barr1,
    const uint32_t* __restrict__ bits2, const int* __restrict__ bb2, int* __restrict__ c2,
    uint64_t* __restrict__ barr2, int n)
{
  int i = blockIdx.x*256 + threadIdx.x;
  if (i >= n) return;
  uint32_t k1 = bits1[i];
  int b = k1 >> 21;
  int p = bb1[b] + atomicAdd(&c1[b], 1);
  barr1[p] = ((uint64_t)k1 << 32) | (uint32_t)i;
  uint32_t k2 = bits2[i];
  b = k2 >> 21;
  p = bb2[b] + atomicAdd(&c2[b], 1);
  barr2[p] = ((uint64_t)k2 << 32) | (uint32_t)i;
}

template<int FINAL>
__global__ __launch_bounds__(256) void rank_bucket_kernel(
    const uint64_t* __restrict__ barr, const int* __restrict__ bptr,
    uint32_t* __restrict__ perm, float* __restrict__ mask_out, int* __restrict__ flag,
    int n)
{
  int p = blockIdx.x*256 + threadIdx.x;
  if (p >= n) return;
  uint64_t mk = barr[p];
  int b = (int)(mk >> 53);
  int p0 = bptr[b], p1 = bptr[b+1];
  int r = p0;
  for (int q = p0; q < p1; ++q) r += (int)(barr[q] < mk);
  uint32_t i = (uint32_t)mk;
  if (!FINAL) {
    perm[r] = i;
  } else if (r < NMASK) {
    uint32_t v = perm[i];
    mask_out[r] = (float)v;
    flag[v] = 1;
  }
}

// ===================== fused MFMA GEMM (all 4 projections, 128-row dual-tile blocks) =====================
// segments: img(157rb x 8ch) txt(157 x 4) itm(157 x 4) usr(235 x 6); rb covers 128 rows.
#define RB2_I 157
#define RB2_U 235
__global__ __launch_bounds__(256) void gemm_all_kernel(
    const float* __restrict__ Xi, const float* __restrict__ Xt,
    const float* __restrict__ Xm, const float* __restrict__ Xu,
    const ushort* __restrict__ wbf,
    ushort* __restrict__ pb_img, ushort* __restrict__ pb_txt,
    ushort* __restrict__ pb_itm, ushort* __restrict__ pb_usr)
{
  __shared__ ushort Xs0[64][72];
  __shared__ ushort Xs1[64][72];
  __shared__ ushort Ws[64][72];
  const int bid = blockIdx.x;
  const float* X; const ushort* Wbf; ushort* pb;
  int N, K, klen, rb, ch;
  if (bid < RB2_I*8) {
    X = Xi; Wbf = wbf; pb = pb_img; N = NI; K = 4096; klen = 512;
    rb = bid % RB2_I; ch = bid / RB2_I;
  } else if (bid < RB2_I*12) {
    int l = bid - RB2_I*8;
    X = Xt; Wbf = wbf + 64*4096; pb = pb_txt; N = NI; K = 768; klen = 192;
    rb = l % RB2_I; ch = l / RB2_I;
  } else if (bid < RB2_I*16) {
    int l = bid - RB2_I*12;
    X = Xm; Wbf = wbf + 64*(4096+768); pb = pb_itm; N = NI; K = 1536; klen = 384;
    rb = l % RB2_I; ch = l / RB2_I;
  } else {
    int l = bid - RB2_I*16;
    X = Xu; Wbf = wbf + 64*(4096+768+1536); pb = pb_usr; N = NU; K = 1536; klen = 256;
    rb = l % RB2_U; ch = l / RB2_U;
  }
  const int tid = threadIdx.x;
  const int row0 = rb * 128;
  const int kbeg = ch * klen;
  const int lane = tid & 63;
  const int wr = tid >> 6;
  const int lrow = lane & 15;
  const int kslot = lane >> 4;
  f32x4 acc0[4] = {f32x4{0,0,0,0},f32x4{0,0,0,0},f32x4{0,0,0,0},f32x4{0,0,0,0}};
  f32x4 acc1[4] = {f32x4{0,0,0,0},f32x4{0,0,0,0},f32x4{0,0,0,0},f32x4{0,0,0,0}};

  const int sr = tid >> 4;          // staging row 0..15 (+16i)
  const int sc = (tid & 15) * 4;    // staging col (floats)
  const int wrow = tid >> 2;        // W staging row 0..63
  const int wcol = (tid & 3) * 16;  // W staging col (elems), 2 x uint4

  for (int k0 = kbeg; k0 < kbeg + klen; k0 += 64) {
#pragma unroll
    for (int i = 0; i < 4; ++i) {
      int r = sr + 16*i;
      int gr0 = row0 + r;
      int gr1 = row0 + 64 + r;
      float4 v0 = make_float4(0.f,0.f,0.f,0.f);
      float4 v1 = make_float4(0.f,0.f,0.f,0.f);
      if (gr0 < N) v0 = *reinterpret_cast<const float4*>(X + (size_t)gr0*K + k0 + sc);
      if (gr1 < N) v1 = *reinterpret_cast<const float4*>(X + (size_t)gr1*K + k0 + sc);
      *reinterpret_cast<uint2*>(&Xs0[r][sc]) = f4_to_bf4(v0);
      *reinterpret_cast<uint2*>(&Xs1[r][sc]) = f4_to_bf4(v1);
    }
    {
      const ushort* wsrc = Wbf + (size_t)wrow*K + k0 + wcol;
      *reinterpret_cast<uint4*>(&Ws[wrow][wcol])   = *reinterpret_cast<const uint4*>(wsrc);
      *reinterpret_cast<uint4*>(&Ws[wrow][wcol+8]) = *reinterpret_cast<const uint4*>(wsrc + 8);
    }
    __syncthreads();
#pragma unroll
    for (int ks = 0; ks < 2; ++ks) {
      int kb = ks*32 + kslot*8;
      bf16x8 a0 = *reinterpret_cast<const bf16x8*>(&Xs0[wr*16 + lrow][kb]);
      bf16x8 a1 = *reinterpret_cast<const bf16x8*>(&Xs1[wr*16 + lrow][kb]);
#pragma unroll
      for (int ct = 0; ct < 4; ++ct) {
        bf16x8 bfr = *reinterpret_cast<const bf16x8*>(&Ws[ct*16 + lrow][kb]);
        acc0[ct] = __builtin_amdgcn_mfma_f32_16x16x32_bf16(a0, bfr, acc0[ct], 0, 0, 0);
        acc1[ct] = __builtin_amdgcn_mfma_f32_16x16x32_bf16(a1, bfr, acc1[ct], 0, 0, 0);
      }
    }
    __syncthreads();
  }
  ushort* pbc = pb + (size_t)ch * N * 64;
#pragma unroll
  for (int ct = 0; ct < 4; ++ct)
#pragma unroll
    for (int j = 0; j < 4; ++j) {
      int r = wr*16 + kslot*4 + j;
      int gr0 = row0 + r, gr1 = row0 + 64 + r;
      if (gr0 < N) pbc[(size_t)gr0*64 + ct*16 + lrow] = f2bf(acc0[ct][j]);
      if (gr1 < N) pbc[(size_t)gr1*64 + ct*16 + lrow] = f2bf(acc1[ct][j]);
    }
}

// ===================== fused reduce for all 4 GEMMs + pack + column means =====================
__global__ __launch_bounds__(256) void reduce4_kernel(
    const ushort* __restrict__ pb_img, const ushort* __restrict__ pb_txt,
    const ushort* __restrict__ pb_itm, const ushort* __restrict__ pb_usr,
    const float* __restrict__ b_img, const float* __restrict__ b_txt,
    const float* __restrict__ b_itm, const float* __restrict__ b_usr,
    const float* __restrict__ idemb,
    float* __restrict__ o_ri, float* __restrict__ o_rt, float* __restrict__ o_rit,
    float* __restrict__ o_ue, ushort* __restrict__ ue_bf,
    uint2* __restrict__ pk_all, float* __restrict__ means)
{
  __shared__ float red[3][256];
  const int nI = NI*64, nUx = NU*64;
  int lane = threadIdx.x & 63;
  float sa = 0.f, sb = 0.f, sc = 0.f;
  for (int i = blockIdx.x*256 + threadIdx.x; i < nUx; i += gridDim.x*256) {
    int lc = i & 63;
    if (i < nI) {
      float s = b_img[lc];
#pragma unroll
      for (int c = 0; c < 8; ++c) s += bf2f(pb_img[(size_t)c*nI + i]);
      o_ri[i] = s;
      float t = b_txt[lc];
#pragma unroll
      for (int c = 0; c < 4; ++c) t += bf2f(pb_txt[(size_t)c*nI + i]);
      o_rt[i] = t;
      float u = b_itm[lc];
#pragma unroll
      for (int c = 0; c < 4; ++c) u += bf2f(pb_itm[(size_t)c*nI + i]);
      o_rit[i] = u;
      pk_all[i] = make_uint2(pk2(s, t), pk2(u, idemb[i]));
      sa += s; sb += t; sc += u;
    }
    float su = b_usr[lc];
#pragma unroll
    for (int c = 0; c < 6; ++c) su += bf2f(pb_usr[(size_t)c*nUx + i]);
    o_ue[i] = su; ue_bf[i] = f2bf(su);
  }
  red[0][threadIdx.x] = sa; red[1][threadIdx.x] = sb; red[2][threadIdx.x] = sc;
  __syncthreads();
  if (threadIdx.x < 64) {
#pragma unroll
    for (int q = 0; q < 3; ++q) {
      float t = red[q][lane]+red[q][64+lane]+red[q][128+lane]+red[q][192+lane];
      if (t != 0.f) atomicAdd(&means[q*64+lane], t * (1.f/NI));
    }
  }
}

// ===================== CSR build (dual-scan) =====================
__global__ __launch_bounds__(256) void scan_block2_kernel(
    const int* __restrict__ cnt_u, const int* __restrict__ cnt_i,
    int* __restrict__ part_u, int* __restrict__ part_i,
    int* __restrict__ bsum_u, int* __restrict__ bsum_i, int nbu)
{
  __shared__ int wsum[4];
  bool isU = (int)blockIdx.x < nbu;
  int blk = isU ? blockIdx.x : blockIdx.x - nbu;
  const int* cnt = isU ? cnt_u : cnt_i;
  int* part = isU ? part_u : part_i;
  int* bsum = isU ? bsum_u : bsum_i;
  int n = isU ? NU : NI;
  int i = blk*256 + threadIdx.x;
  int lane = threadIdx.x & 63;
  int w = threadIdx.x >> 6;
  int v = (i < n) ? cnt[i] : 0;
  int s = v;
#pragma unroll
  for (int off = 1; off < 64; off <<= 1) {
    int t = __shfl_up(s, off);
    if (lane >= off) s += t;
  }
  if (lane == 63) wsum[w] = s;
  __syncthreads();
  int wo = 0;
#pragma unroll
  for (int k = 0; k < 4; ++k) if (k < w) wo += wsum[k];
  if (i < n) part[i] = wo + s - v;
  if (threadIdx.x == 255) bsum[blk] = wo + s;
}

__global__ __launch_bounds__(64) void exscan2b_kernel(
    const int* __restrict__ bs_u, int* __restrict__ bp_u, int nbu,
    const int* __restrict__ bs_i, int* __restrict__ bp_i, int nbi)
{
  const int* cnt = blockIdx.x ? bs_i : bs_u;
  int* ptr = blockIdx.x ? bp_i : bp_u;
  int n = blockIdx.x ? nbi : nbu;
  int lane = threadIdx.x;
  int carry = 0;
  for (int base = 0; base < n; base += 64) {
    int i = base + lane;
    int v = (i < n) ? cnt[i] : 0;
    int s = v;
#pragma unroll
    for (int off = 1; off < 64; off <<= 1) {
      int t = __shfl_up(s, off);
      if (lane >= off) s += t;
    }
    if (i < n) ptr[i] = carry + s - v;
    carry += __shfl(s, 63);
  }
  if (lane == 0) ptr[n] = carry;
}

__global__ __launch_bounds__(256) void scan_add2_kernel(
    const int* __restrict__ part_u, const int* __restrict__ bp_u,
    const int* __restrict__ part_i, const int* __restrict__ bp_i,
    int* __restrict__ ptr_u, int* __restrict__ cur_u,
    int* __restrict__ ptr_i, int* __restrict__ cur_i, int nbu, int nbi)
{
  bool isU = (int)blockIdx.x < nbu;
  int blk = isU ? blockIdx.x : blockIdx.x - nbu;
  int n = isU ? NU : NI;
  const int* part = isU ? part_u : part_i;
  const int* bp = isU ? bp_u : bp_i;
  int* ptr = isU ? ptr_u : ptr_i;
  int* cur = isU ? cur_u : cur_i;
  int i = blk*256 + threadIdx.x;
  if (i < n) { int v = part[i] + bp[blk]; ptr[i] = v; cur[i] = v; }
  if (i == 0) ptr[n] = bp[isU ? nbu : nbi];
}

__global__ __launch_bounds__(256) void scatter_kernel(
    const int* __restrict__ rows, const int* __restrict__ cols, const float* __restrict__ vals,
    int* __restrict__ cur_u, int* __restrict__ cur_i,
    int* __restrict__ idx_u, float* __restrict__ val_u,
    int* __restrict__ idx_i, float* __restrict__ val_i, int nnz)
{
  int k = blockIdx.x*256 + threadIdx.x;
  if (k < nnz) {
    int r = rows[k], c = cols[k];
    float v = vals[k];
    int pu = atomicAdd(&cur_u[r], 1);
    idx_u[pu] = c; val_u[pu] = v;
    int pi = atomicAdd(&cur_i[c], 1);
    idx_i[pi] = r; val_i[pi] = v;
  }
}

// ===================== fused SpMMs (uint2 bf16 gathers, 8/4/1 cascade unroll) =====================
__global__ __launch_bounds__(256) void spmm_user1_kernel(
    const int* __restrict__ ptr, const int* __restrict__ idx, const float* __restrict__ val,
    const uint2* __restrict__ pka,
    const int* __restrict__ flag, const float* __restrict__ means,
    float* __restrict__ iu, float* __restrict__ tu, float* __restrict__ ufi, float* __restrict__ u1,
    uint2* __restrict__ qa, int nrows)
{
  int row = blockIdx.x*4 + (threadIdx.x >> 6);
  int lane = threadIdx.x & 63;
  if (row >= nrows) return;
  int p0 = ptr[row], p1 = ptr[row+1];
  float m0 = means[lane], m1 = means[64+lane], m2 = means[128+lane];
  float a0=0.f, a1=0.f, a2=0.f, a3=0.f;
#define U1STEP(gg,ff,ww) { float x0,x1,x2, x3 = hibf(gg.y); \
    if (ff) { x0=m0; x1=m1; x2=m2; } \
    else { x0=lobf(gg.x); x1=hibf(gg.x); x2=lobf(gg.y); } \
    a0=fmaf(ww,x0,a0); a1=fmaf(ww,x1,a1); a2=fmaf(ww,x2,a2); a3=fmaf(ww,x3,a3); }
  int p = p0;
  for (; p + 8 <= p1; p += 8) {
    int j[8]; float w[8]; int f[8]; uint2 g[8];
#pragma unroll
    for (int q = 0; q < 8; ++q) { j[q]=idx[p+q]; w[q]=val[p+q]; }
#pragma unroll
    for (int q = 0; q < 8; ++q) { f[q]=flag[j[q]]; g[q]=pka[(size_t)j[q]*64+lane]; }
#pragma unroll
    for (int q = 0; q < 8; ++q) U1STEP(g[q],f[q],w[q])
  }
  for (; p + 4 <= p1; p += 4) {
    int j0=idx[p+0], j1=idx[p+1], j2=idx[p+2], j3=idx[p+3];
    float w0=val[p+0], w1=val[p+1], w2=val[p+2], w3=val[p+3];
    int f0=flag[j0], f1=flag[j1], f2=flag[j2], f3=flag[j3];
    uint2 g0=pka[(size_t)j0*64+lane], g1=pka[(size_t)j1*64+lane];
    uint2 g2=pka[(size_t)j2*64+lane], g3=pka[(size_t)j3*64+lane];
    U1STEP(g0,f0,w0) U1STEP(g1,f1,w1) U1STEP(g2,f2,w2) U1STEP(g3,f3,w3)
  }
  for (; p < p1; ++p) {
    int j = idx[p]; float v = val[p];
    uint2 g = pka[(size_t)j*64 + lane];
    int f = flag[j];
    U1STEP(g,f,v)
  }
#undef U1STEP
  size_t o = (size_t)row*64 + lane;
  iu[o]=a0; tu[o]=a1; ufi[o]=a2; u1[o]=a3;
  qa[o] = make_uint2(pk2(a0, a1), pk2(a2, a3));
}

__global__ __launch_bounds__(256) void spmm_item1_kernel(
    const int* __restrict__ ptr, const int* __restrict__ idx, const float* __restrict__ val,
    const uint2* __restrict__ qa, const ushort* __restrict__ ueh,
    float* __restrict__ ii, float* __restrict__ ti, float* __restrict__ ifo,
    float* __restrict__ i1, float* __restrict__ ip,
    uint32_t* __restrict__ qip1, int nrows)
{
  int row = blockIdx.x*4 + (threadIdx.x >> 6);
  int lane = threadIdx.x & 63;
  if (row >= nrows) return;
  int p0 = ptr[row], p1 = ptr[row+1];
  float a0=0.f, a1=0.f, a2=0.f, a3=0.f, a4=0.f;
#define I1STEP(gg,uu,ww) { \
    a0=fmaf(ww,lobf(gg.x),a0); a1=fmaf(ww,hibf(gg.x),a1); \
    a2=fmaf(ww,lobf(gg.y),a2); a3=fmaf(ww,hibf(gg.y),a3); \
    a4=fmaf(ww,bf2f(uu),a4); }
  int p = p0;
  for (; p + 8 <= p1; p += 8) {
    int j[8]; float w[8]; uint2 g[8]; ushort u[8];
#pragma unroll
    for (int q = 0; q < 8; ++q) { j[q]=idx[p+q]; w[q]=val[p+q]; }
#pragma unroll
    for (int q = 0; q < 8; ++q) {
      size_t b = (size_t)j[q]*64+lane;
      g[q]=qa[b]; u[q]=ueh[b];
    }
#pragma unroll
    for (int q = 0; q < 8; ++q) I1STEP(g[q],u[q],w[q])
  }
  for (; p + 4 <= p1; p += 4) {
    int j0=idx[p+0], j1=idx[p+1], j2=idx[p+2], j3=idx[p+3];
    float w0=val[p+0], w1=val[p+1], w2=val[p+2], w3=val[p+3];
    size_t b0=(size_t)j0*64+lane, b1=(size_t)j1*64+lane, b2=(size_t)j2*64+lane, b3=(size_t)j3*64+lane;
    uint2 g0=qa[b0], g1=qa[b1], g2=qa[b2], g3=qa[b3];
    ushort u0=ueh[b0], u1_=ueh[b1], u2_=ueh[b2], u3_=ueh[b3];
    I1STEP(g0,u0,w0) I1STEP(g1,u1_,w1) I1STEP(g2,u2_,w2) I1STEP(g3,u3_,w3)
  }
  for (; p < p1; ++p) {
    int j = idx[p]; float v = val[p];
    size_t b = (size_t)j*64 + lane;
    uint2 g = qa[b]; ushort u = ueh[b];
    I1STEP(g,u,v)
  }
#undef I1STEP
  size_t o = (size_t)row*64 + lane;
  ii[o]=a0; ti[o]=a1; ifo[o]=a2; i1[o]=a3; ip[o]=a4;
  qip1[o] = pk2(a4, a3);
}

__global__ __launch_bounds__(256) void user2_kernel(
    const int* __restrict__ ptr, const int* __restrict__ idx, const float* __restrict__ val,
    const uint32_t* __restrict__ qip1,
    const float* __restrict__ idemb, const float* __restrict__ u1,
    const float* __restrict__ iu, const float* __restrict__ tu, const float* __restrict__ ufi,
    float* __restrict__ up, ushort* __restrict__ u2h, float* __restrict__ ug, int nrows)
{
  int row = blockIdx.x*4 + (threadIdx.x >> 6);
  int lane = threadIdx.x & 63;
  if (row >= nrows) return;
  int p0 = ptr[row], p1 = ptr[row+1];
  float aup=0.f, au2=0.f;
  int p = p0;
  for (; p + 4 <= p1; p += 4) {
    int j0=idx[p+0], j1=idx[p+1], j2=idx[p+2], j3=idx[p+3];
    float w0=val[p+0], w1=val[p+1], w2=val[p+2], w3=val[p+3];
    uint32_t g0=qip1[(size_t)j0*64+lane], g1=qip1[(size_t)j1*64+lane];
    uint32_t g2=qip1[(size_t)j2*64+lane], g3=qip1[(size_t)j3*64+lane];
    aup=fmaf(w0,lobf(g0),aup); au2=fmaf(w0,hibf(g0),au2);
    aup=fmaf(w1,lobf(g1),aup); au2=fmaf(w1,hibf(g1),au2);
    aup=fmaf(w2,lobf(g2),aup); au2=fmaf(w2,hibf(g2),au2);
    aup=fmaf(w3,lobf(g3),aup); au2=fmaf(w3,hibf(g3),au2);
  }
  for (; p < p1; ++p) {
    int j = idx[p]; float v = val[p];
    uint32_t g = qip1[(size_t)j*64 + lane];
    aup = fmaf(v, lobf(g), aup);
    au2 = fmaf(v, hibf(g), au2);
  }
  float m = au2;
#pragma unroll
  for (int o2=32;o2;o2>>=1) m = fmaxf(m, __shfl_xor(m, o2));
  float e = expf(au2 - m);
  float s = e;
#pragma unroll
  for (int o2=32;o2;o2>>=1) s += __shfl_xor(s, o2);
  float u2 = e / s;
  size_t o = (size_t)row*64 + lane;
  up[o] = aup; u2h[o] = f2bf(u2);
  float e0 = idemb[o], e1 = u1[o];
  float v1 = iu[o], v2 = tu[o], v3 = aup, v4 = ufi[o];
  float n1=v1*v1, n2=v2*v2, n3=v3*v3, n4=v4*v4;
#pragma unroll
  for (int o2=32;o2;o2>>=1) {
    n1 += __shfl_xor(n1, o2); n2 += __shfl_xor(n2, o2);
    n3 += __shfl_xor(n3, o2); n4 += __shfl_xor(n4, o2);
  }
  n1 = fmaxf(sqrtf(n1), 1e-12f); n2 = fmaxf(sqrtf(n2), 1e-12f);
  n3 = fmaxf(sqrtf(n3), 1e-12f); n4 = fmaxf(sqrtf(n4), 1e-12f);
  ug[o] = (e0+e1+u2)*(1.f/3.f)
        + 0.02f*(v1/n1) + 0.02f*(v2/n2)
        + 0.30f*(v3/n3) + 0.30f*(v4/n4);
}

__global__ __launch_bounds__(256) void item2_kernel(
    const int* __restrict__ ptr, const int* __restrict__ idx, const float* __restrict__ val,
    const ushort* __restrict__ u2h,
    const float* __restrict__ idemb, const float* __restrict__ i1,
    const float* __restrict__ ii, const float* __restrict__ ti,
    const float* __restrict__ ip, const float* __restrict__ ifo,
    float* __restrict__ ig, int nrows)
{
  int row = blockIdx.x*4 + (threadIdx.x >> 6);
  int lane = threadIdx.x & 63;
  if (row >= nrows) return;
  int p0 = ptr[row], p1 = ptr[row+1];
  float ai2=0.f;
  int p = p0;
  for (; p + 4 <= p1; p += 4) {
    int j0=idx[p+0], j1=idx[p+1], j2=idx[p+2], j3=idx[p+3];
    float w0=val[p+0], w1=val[p+1], w2=val[p+2], w3=val[p+3];
    ushort h0=u2h[(size_t)j0*64+lane], h1=u2h[(size_t)j1*64+lane];
    ushort h2=u2h[(size_t)j2*64+lane], h3=u2h[(size_t)j3*64+lane];
    ai2=fmaf(w0,bf2f(h0),ai2); ai2=fmaf(w1,bf2f(h1),ai2);
    ai2=fmaf(w2,bf2f(h2),ai2); ai2=fmaf(w3,bf2f(h3),ai2);
  }
  for (; p < p1; ++p) {
    int j = idx[p]; float v = val[p];
    ai2 = fmaf(v, bf2f(u2h[(size_t)j*64 + lane]), ai2);
  }
  float m = ai2;
#pragma unroll
  for (int o2=32;o2;o2>>=1) m = fmaxf(m, __shfl_xor(m, o2));
  float e = expf(ai2 - m);
  float s = e;
#pragma unroll
  for (int o2=32;o2;o2>>=1) s += __shfl_xor(s, o2);
  float i2 = e / s;
  size_t o = (size_t)row*64 + lane;
  float e0 = idemb[o], e1 = i1[o];
  float v1 = ii[o], v2 = ti[o], v3 = ip[o], v4 = ifo[o];
  float n1=v1*v1, n2=v2*v2, n3=v3*v3, n4=v4*v4;
#pragma unroll
  for (int o2=32;o2;o2>>=1) {
    n1 += __shfl_xor(n1, o2); n2 += __shfl_xor(n2, o2);
    n3 += __shfl_xor(n3, o2); n4 += __shfl_xor(n4, o2);
  }
  n1 = fmaxf(sqrtf(n1), 1e-12f); n2 = fmaxf(sqrtf(n2), 1e-12f);
  n3 = fmaxf(sqrtf(n3), 1e-12f); n4 = fmaxf(sqrtf(n4), 1e-12f);
  ig[o] = (e0+e1+i2)*(1.f/3.f)
        + 0.02f*(v1/n1) + 0.02f*(v2/n2)
        + 0.30f*(v3/n3) + 0.30f*(v4/n4);
}

// ===================== host =====================
extern "C" void kernel_launch(void* const* d_in, const int* in_sizes, int n_in,
                              void* d_out, int out_size, void* d_ws, size_t ws_size,
                              hipStream_t stream)
{
  const int*   ui_rows     = (const int*)d_in[0];
  const int*   ui_cols     = (const int*)d_in[1];
  const float* ui_vals     = (const float*)d_in[2];
  const float* image_feats = (const float*)d_in[3];
  const float* text_feats  = (const float*)d_in[4];
  const float* user_feats0 = (const float*)d_in[5];
  const float* item_title  = (const float*)d_in[6];
  const float* W_img = (const float*)d_in[7];
  const float* b_img = (const float*)d_in[8];
  const float* W_txt = (const float*)d_in[9];
  const float* b_txt = (const float*)d_in[10];
  const float* W_usr = (const float*)d_in[11];
  const float* b_usr = (const float*)d_in[12];
  const float* W_itm = (const float*)d_in[13];
  const float* b_itm = (const float*)d_in[14];
  const float* user_id_emb = (const float*)d_in[15];
  const float* item_id_emb = (const float*)d_in[16];
  const int nnz = in_sizes[0];

  float* out = (float*)d_out;
  const size_t OU = (size_t)NU*64, OI = (size_t)NI*64;
  size_t off = 0;
  float* o_ug   = out + off; off += OU;
  float* o_ig   = out + off; off += OI;
  float* o_ii   = out + off; off += OI;
  float* o_ti   = out + off; off += OI;
  float* o_iu   = out + off; off += OU;
  float* o_tu   = out + off; off += OU;
  float* o_ue   = out + off; off += OU;
  float* o_ifo  = out + off; off += OI;
  float* o_up   = out + off; off += OU;
  float* o_ip   = out + off; off += OI;
  float* o_ufi  = out + off; off += OU;
  float* o_mask = out + off; off += NMASK;
  float* o_ri   = out + off; off += OI;
  float* o_rt   = out + off; off += OI;
  float* o_rit  = out + off; off += OI;

  char* wp = (char*)d_ws;
  auto walloc = [&](size_t bytes) -> char* {
    char* r = wp; wp += (bytes + 255) & ~(size_t)255; return r;
  };
  // --- zero zone ---
  int*   cnt_u = (int*)  walloc((size_t)NU*4);
  int*   cnt_i = (int*)  walloc((size_t)NI*4);
  int*   flag  = (int*)  walloc((size_t)NI*4);
  float* means = (float*)walloc(3*64*4);
  int*   h1    = (int*)  walloc(NBUCK*4);
  int*   c1    = (int*)  walloc(NBUCK*4);
  int*   h2    = (int*)  walloc(NBUCK*4);
  int*   c2    = (int*)  walloc(NBUCK*4);
  size_t zero_bytes = (size_t)(wp - (char*)d_ws);
  // --- rest ---
  uint32_t* bits1 = (uint32_t*)walloc((size_t)NI*4);
  uint32_t* bits2 = (uint32_t*)walloc((size_t)NI*4);
  uint32_t* permA = (uint32_t*)walloc((size_t)NI*4);
  uint64_t* barr1 = (uint64_t*)walloc((size_t)NI*8);
  uint64_t* barr2 = (uint64_t*)walloc((size_t)NI*8);
  int*   bb1   = (int*)  walloc((NBUCK+1)*4);
  int*   bb2   = (int*)  walloc((NBUCK+1)*4);
  int*   ptr_u = (int*)  walloc((size_t)(NU+1)*4);
  int*   ptr_i = (int*)  walloc((size_t)(NI+1)*4);
  int*   cur_u = (int*)  walloc((size_t)NU*4);
  int*   cur_i = (int*)  walloc((size_t)NI*4);
  int*   idx_u = (int*)  walloc((size_t)nnz*4);
  float* val_u = (float*)walloc((size_t)nnz*4);
  int*   idx_i = (int*)  walloc((size_t)nnz*4);
  float* val_i = (float*)walloc((size_t)nnz*4);
  float* u1    = (float*)walloc(OU*4);
  float* i1    = (float*)walloc(OI*4);
  int*   part_u = (int*) walloc((size_t)NU*4);
  int*   part_i = (int*) walloc((size_t)NI*4);
  int*   bsum_u = (int*) walloc(128*4);
  int*   bsum_i = (int*) walloc(128*4);
  int*   bp_u   = (int*) walloc(129*4);
  int*   bp_i   = (int*) walloc(129*4);
  ushort* wbf  = (ushort*)walloc((size_t)WTOTAL*2);
  uint2* pk_all = (uint2*)walloc(OI*8);
  uint2* q_all  = (uint2*)walloc(OU*8);
  uint32_t* qip1 = (uint32_t*)walloc(OI*4);
  ushort*   ue_bf = (ushort*)walloc(OU*2);
  ushort*   u2h   = (ushort*)walloc(OU*2);
  ushort* pb_img = (ushort*)walloc((size_t)8*NI*64*2);
  ushort* pb_txt = (ushort*)walloc((size_t)4*NI*64*2);
  ushort* pb_itm = (ushort*)walloc((size_t)4*NI*64*2);
  ushort* pb_usr = (ushort*)walloc((size_t)6*NU*64*2);

  hipMemsetAsync(d_ws, 0, zero_bytes, stream);

  // --- prep: threefry + W->bf16 + edge histogram (one launch) ---
  prep_kernel<<<512, 256, 0, stream>>>(bits1, bits2, h1, h2,
      W_img, W_txt, W_itm, W_usr, wbf, ui_rows, ui_cols, cnt_u, cnt_i, nnz);

  // --- mask_nodes: bucketed stable sorts ---
  const int GB = cdiv(NI,256);
  exscan2_kernel<<<2, 64, 0, stream>>>(h1, bb1, h2, bb2);
  scatter12_kernel<<<GB, 256, 0, stream>>>(bits1, bb1, c1, barr1, bits2, bb2, c2, barr2, NI);
  rank_bucket_kernel<0><<<GB, 256, 0, stream>>>(barr1, bb1, permA, nullptr, nullptr, NI);
  rank_bucket_kernel<1><<<GB, 256, 0, stream>>>(barr2, bb2, permA, o_mask, flag, NI);

  // --- all 4 projections in one launch (128-row dual-tile blocks, bf16 partials) ---
  gemm_all_kernel<<<RB2_I*16 + RB2_U*6, 256, 0, stream>>>(
      image_feats, text_feats, item_title, user_feats0, wbf,
      pb_img, pb_txt, pb_itm, pb_usr);
  reduce4_kernel<<<1024, 256, 0, stream>>>(pb_img, pb_txt, pb_itm, pb_usr,
      b_img, b_txt, b_itm, b_usr, item_id_emb,
      o_ri, o_rt, o_rit, o_ue, ue_bf, pk_all, means);

  // --- CSR build (dual-scan pipeline; hist already done in prep) ---
  {
    int nbu = cdiv(NU,256), nbi = cdiv(NI,256);
    scan_block2_kernel<<<nbu+nbi, 256, 0, stream>>>(cnt_u, cnt_i, part_u, part_i, bsum_u, bsum_i, nbu);
    exscan2b_kernel<<<2, 64, 0, stream>>>(bsum_u, bp_u, nbu, bsum_i, bp_i, nbi);
    scan_add2_kernel<<<nbu+nbi, 256, 0, stream>>>(part_u, bp_u, part_i, bp_i,
        ptr_u, cur_u, ptr_i, cur_i, nbu, nbi);
  }
  scatter_kernel<<<cdiv(nnz,256), 256, 0, stream>>>(ui_rows, ui_cols, ui_vals,
      cur_u, cur_i, idx_u, val_u, idx_i, val_i, nnz);

  const int GU = cdiv(NU,4), GI = cdiv(NI,4);
  spmm_user1_kernel<<<GU,256,0,stream>>>(ptr_u, idx_u, val_u,
      pk_all, flag, means,
      o_iu, o_tu, o_ufi, u1, q_all, NU);
  spmm_item1_kernel<<<GI,256,0,stream>>>(ptr_i, idx_i, val_i,
      q_all, ue_bf,
      o_ii, o_ti, o_ifo, i1, o_ip, qip1, NI);
  user2_kernel<<<GU,256,0,stream>>>(ptr_u, idx_u, val_u,
      qip1, user_id_emb, u1, o_iu, o_tu, o_ufi,
      o_up, u2h, o_ug, NU);
  item2_kernel<<<GI,256,0,stream>>>(ptr_i, idx_i, val_i,
      u2h, item_id_emb, i1, o_ii, o_ti, o_ip, o_ifo,
      o_ig, NI);
}